// Round 11
// baseline (416.484 us; speedup 1.0000x reference)
//
#include <hip/hip_runtime.h>
#include <cstdint>
#include <cstddef>

static inline size_t align_up(size_t v, size_t a) { return (v + a - 1) & ~(a - 1); }

#define BCAP 3072  // fixed slots per 128-node bucket; mean occupancy 2048, sigma~45 -> +22 sigma margin

typedef __attribute__((ext_vector_type(8))) short short8;
typedef __attribute__((ext_vector_type(4))) float f32x4;
typedef __attribute__((ext_vector_type(2))) float f32x2;

// bf16 helpers (RNE)
__device__ inline unsigned short bf16_1(float x) {
  unsigned u = __float_as_uint(x);
  u += 0x7FFFu + ((u >> 16) & 1u);
  return (unsigned short)(u >> 16);
}
// HW packed cvt: 2 f32 -> 1 uint of 2 bf16 (1 instr vs ~8 for the bit-hack pair).
__device__ inline unsigned cvt_pk_bf16(float lo, float hi) {
  unsigned r;
  asm("v_cvt_pk_bf16_f32 %0, %1, %2" : "=v"(r) : "v"(lo), "v"(hi));
  return r;
}

// fp8 e4m3 (OCP) helpers — HW cvt is RNE (unbiased through mean-pool)
__device__ inline unsigned char fp8_1(float x) {
  return (unsigned char)(__builtin_amdgcn_cvt_pk_fp8_f32(x, x, 0, false) & 0xFF);
}

// ---------------- weight prep: transpose to [c][k] bf16; zero cnt[N] ----------------
__global__ void prep_kernel(const float* __restrict__ W1, const float* __restrict__ W2,
                            unsigned short* __restrict__ w1t, unsigned short* __restrict__ w2t,
                            int* __restrict__ cnt, int N) {
  int t = blockIdx.x * 256 + threadIdx.x;
  if (t < 16384) {
    int c = t >> 7, k = t & 127;
    w1t[t] = bf16_1(W1[(size_t)k * 128 + c]);
  } else if (t < 20480) {
    int i = t - 16384;
    int c = i >> 7, k = i & 127;
    w2t[i] = bf16_1(W2[(size_t)k * 32 + c]);
  }
  for (int i = t; i < N; i += gridDim.x * 256) cnt[i] = 0;  // degree counters
}

__device__ inline int load_edge(const void* eidx, int is64, size_t idx) {
  if (is64) return (int)((const long long*)eidx)[idx];
  return ((const int*)eidx)[idx];
}

// ======= CSR build v2: 3-phase histogram/scan/scatter =======
// R10 PMC showed the old 2-phase bucket sort at 74 µs with VALUBusy 8.8%,
// 1.9M LDS-conflict cycles, and ~610K same-address cross-XCD atomics (780
// contenders each) in the reservation step. The 3-phase build spreads atomics
// over N=100K addresses (avg 16/addr) and removes the `packed` intermediate.

// ---- phase 1: per-dst degree histogram (fused with gemm1: no LDS, independent)
__device__ void hist_body(int* s_is64, const void* eidx, int E,
                          int* __restrict__ cnt, int bid) {
  const int t = threadIdx.x;
  const int chunk0 = bid * 4096;
  const int cntE = min(4096, E - chunk0);
  if (t == 0) *s_is64 = 1;
  __syncthreads();
  {
    int nchk = min(cntE, 256);
    for (int i = t; i < nchk; i += 256)
      if (((const unsigned*)eidx)[2 * (size_t)(chunk0 + i) + 1] != 0u) *s_is64 = 0;  // benign race
  }
  __syncthreads();
  const int is64 = *s_is64;
#pragma unroll
  for (int k = 0; k < 16; ++k) {
    int li = k * 256 + t;
    if (li < cntE) {
      int dv = load_edge(eidx, is64, (size_t)E + chunk0 + li);
      atomicAdd(&cnt[dv], 1);
    }
  }
}

// ---- gemm1 body (MFMA bf16): h1f = fp8(bf16(x) @ bf16(W1)), + al1 fused
__device__ void gemm1_body(char* smem,
    const float* __restrict__ x, const unsigned short* __restrict__ w1t,
    const float* __restrict__ a1s, const float* __restrict__ a1d,
    unsigned char* __restrict__ h1f, float* __restrict__ al1s, float* __restrict__ al1d,
    int N, int bid) {
  unsigned short* sw = (unsigned short*)smem;    // 128*136
  unsigned short* sx = sw + 128 * 136;           // 64*136; reused as fp8 tile
  unsigned char* ftile = (unsigned char*)sx;
  const int t = threadIdx.x;
  const int row0 = bid * 64;
  for (int i = t; i < 4096; i += 256) {
    int c = i >> 5, k4 = (i & 31) * 4;
    *(ushort4*)&sw[c * 136 + k4] = *(const ushort4*)&w1t[c * 128 + k4];
  }
  for (int i = t; i < 2048; i += 256) {
    int r = i >> 5, c4 = (i & 31) * 4;
    float4 v = make_float4(0.f, 0.f, 0.f, 0.f);
    if (row0 + r < N) v = *(const float4*)(x + (size_t)(row0 + r) * 128 + c4);
    uint2 b;                       // packed HW cvt: 2 instrs for 4 values
    b.x = cvt_pk_bf16(v.x, v.y);
    b.y = cvt_pk_bf16(v.z, v.w);
    *(uint2*)&sx[r * 136 + c4] = b;
  }
  __syncthreads();
  const int lane = t & 63, wave = t >> 6;
  const int m = lane & 15, quad = lane >> 4;
  const unsigned short* arow = &sx[(wave * 16 + m) * 136];
  short8 A[4];
#pragma unroll
  for (int ks = 0; ks < 4; ++ks) A[ks] = *(const short8*)&arow[ks * 32 + quad * 8];
  __syncthreads();  // all waves have A in regs; sx region now writable as fp8 tile
  const int lrow = wave * 16 + quad * 4;
#pragma unroll
  for (int nt = 0; nt < 8; ++nt) {
    const unsigned short* brow = &sw[(nt * 16 + m) * 136];
    f32x4 acc = {0.f, 0.f, 0.f, 0.f};
#pragma unroll
    for (int ks = 0; ks < 4; ++ks) {
      short8 B = *(const short8*)&brow[ks * 32 + quad * 8];
      acc = __builtin_amdgcn_mfma_f32_16x16x32_bf16(A[ks], B, acc, 0, 0, 0);
    }
#pragma unroll
    for (int r = 0; r < 4; ++r)
      ftile[(lrow + r) * 128 + nt * 16 + m] = fp8_1(acc[r]);
  }
  __syncthreads();
  // coalesced flush + fused al1 (from the same fp8 values the gather will see)
#pragma unroll
  for (int it = 0; it < 2; ++it) {
    int row = it * 32 + (t >> 3);
    int chunk = t & 7;            // 16-byte chunk = 16 cols; head = chunk>>1
    uint4 v = *(const uint4*)&ftile[row * 128 + chunk * 16];
    int grow = row0 + row;
    if (grow < N) *(uint4*)&h1f[(size_t)grow * 128 + chunk * 16] = v;
    unsigned w[4] = {v.x, v.y, v.z, v.w};
    float ps = 0.f, pd = 0.f;
    int cb = chunk * 16;
#pragma unroll
    for (int q = 0; q < 4; ++q) {
      f32x2 lo = __builtin_amdgcn_cvt_pk_f32_fp8((int)w[q], false);
      f32x2 hi = __builtin_amdgcn_cvt_pk_f32_fp8((int)w[q], true);
      int c = cb + q * 4;
      ps += lo[0] * a1s[c] + lo[1] * a1s[c + 1] + hi[0] * a1s[c + 2] + hi[1] * a1s[c + 3];
      pd += lo[0] * a1d[c] + lo[1] * a1d[c + 1] + hi[0] * a1d[c + 2] + hi[1] * a1d[c + 3];
    }
    ps += __shfl_xor(ps, 1); pd += __shfl_xor(pd, 1);  // pair chunks c, c^1 -> full head
    if ((chunk & 1) == 0 && grow < N) {
      int head = chunk >> 1;
      al1s[(size_t)grow * 4 + head] = ps;
      al1d[(size_t)grow * 4 + head] = pd;
    }
  }
}

__global__ __launch_bounds__(256) void fused_hist_gemm1(
    const void* eidx, int E, int* __restrict__ cnt, int NHB,
    const float* __restrict__ x, const unsigned short* __restrict__ w1t,
    const float* __restrict__ a1s, const float* __restrict__ a1d,
    unsigned char* __restrict__ h1f, float* __restrict__ al1s, float* __restrict__ al1d,
    int N) {
  __shared__ __align__(16) char smem[52224];   // gemm1's footprint; hist uses 4 B
  int bid = blockIdx.x;
  if (bid < NHB) {
    hist_body((int*)smem, eidx, E, cnt, bid);
  } else {
    gemm1_body(smem, x, w1t, a1s, a1d, h1f, al1s, al1d, N, bid - NHB);
  }
}

// ---- phase 2: per-bucket scan of 128 counts -> rowbeg/rowend; cnt becomes fillp
__global__ __launch_bounds__(128) void buildRow_kernel(int* __restrict__ cntfill,
                                                       int* __restrict__ rowbeg,
                                                       int* __restrict__ rowend, int N) {
  __shared__ int ex[128];
  const int b = blockIdx.x, t = threadIdx.x;
  const int node0 = b << 7;
  const int nn = min(128, N - node0);
  int c = (t < nn) ? cntfill[node0 + t] : 0;
  ex[t] = c;
  __syncthreads();
  for (int off = 1; off < 128; off <<= 1) {
    int u = (t >= off) ? ex[t - off] : 0;
    __syncthreads();
    ex[t] += u;
    __syncthreads();
  }
  int rb = b * BCAP + ex[t] - c;   // exclusive prefix within bucket
  if (t < nn) {
    rowbeg[node0 + t] = rb;
    rowend[node0 + t] = rb + c;
    cntfill[node0 + t] = rb;       // fill pointer for the scatter phase
  }
}

// ---- phase 3: scatter edges into csr via per-row fill pointers (low contention:
// avg 16 atomics per address, vs 780 in the old bucket-reservation scheme)
__global__ __launch_bounds__(256) void scatter_kernel(const void* eidx, int E,
                                                      int* __restrict__ fillp,
                                                      int* __restrict__ csr) {
  __shared__ int s_is64;
  const int t = threadIdx.x;
  const int chunk0 = blockIdx.x * 2048;
  const int cntE = min(2048, E - chunk0);
  if (t == 0) s_is64 = 1;
  __syncthreads();
  {
    int nchk = min(cntE, 256);
    for (int i = t; i < nchk; i += 256)
      if (((const unsigned*)eidx)[2 * (size_t)(chunk0 + i) + 1] != 0u) s_is64 = 0;  // benign race
  }
  __syncthreads();
  const int is64 = s_is64;
#pragma unroll
  for (int k = 0; k < 8; ++k) {
    int li = k * 256 + t;
    if (li < cntE) {
      int sv = load_edge(eidx, is64, (size_t)chunk0 + li);
      int dv = load_edge(eidx, is64, (size_t)E + chunk0 + li);
      int pos = atomicAdd(&fillp[dv], 1);
      csr[pos] = sv;
    }
  }
}

// ---------------- GEMM2 (MFMA bf16): h2f = fp8(houtb @ bf16(W2)), + al2 fused ----------------
__global__ __launch_bounds__(256) void gemm2_mfma(
    const unsigned* __restrict__ houtb, const unsigned short* __restrict__ w2t,
    const float* __restrict__ a2s, const float* __restrict__ a2d,
    unsigned char* __restrict__ h2f, float* __restrict__ al2s, float* __restrict__ al2d, int N) {
  __shared__ unsigned short sw[32 * 136];
  __shared__ unsigned short sx[64 * 136];
  unsigned char* ftile = (unsigned char*)sx;  // 2 KB fp8 tile
  const int t = threadIdx.x;
  const int row0 = blockIdx.x * 64;
  for (int i = t; i < 1024; i += 256) {
    int c = i >> 5, k4 = (i & 31) * 4;
    *(ushort4*)&sw[c * 136 + k4] = *(const ushort4*)&w2t[c * 128 + k4];
  }
  for (int i = t; i < 2048; i += 256) {
    int r = i >> 5, d2 = (i & 31) * 2;
    uint2 v = make_uint2(0u, 0u);
    if (row0 + r < N) v = *(const uint2*)(houtb + (size_t)(row0 + r) * 64 + d2);
    *(uint2*)&sx[r * 136 + d2 * 2] = v;
  }
  __syncthreads();
  const int lane = t & 63, wave = t >> 6;
  const int m = lane & 15, quad = lane >> 4;
  const unsigned short* arow = &sx[(wave * 16 + m) * 136];
  short8 A[4];
#pragma unroll
  for (int ks = 0; ks < 4; ++ks) A[ks] = *(const short8*)&arow[ks * 32 + quad * 8];
  __syncthreads();
  const int lrow = wave * 16 + quad * 4;
#pragma unroll
  for (int nt = 0; nt < 2; ++nt) {
    const unsigned short* brow = &sw[(nt * 16 + m) * 136];
    f32x4 acc = {0.f, 0.f, 0.f, 0.f};
#pragma unroll
    for (int ks = 0; ks < 4; ++ks) {
      short8 B = *(const short8*)&brow[ks * 32 + quad * 8];
      acc = __builtin_amdgcn_mfma_f32_16x16x32_bf16(A[ks], B, acc, 0, 0, 0);
    }
#pragma unroll
    for (int r = 0; r < 4; ++r)
      ftile[(lrow + r) * 32 + nt * 16 + m] = fp8_1(acc[r]);
  }
  __syncthreads();
  if (t < 128) {
    int row = t >> 1, chunk = t & 1;  // 16-byte chunk = 16 of 32 cols
    uint4 v = *(const uint4*)&ftile[row * 32 + chunk * 16];
    int grow = row0 + row;
    if (grow < N) *(uint4*)&h2f[(size_t)grow * 32 + chunk * 16] = v;
    unsigned w[4] = {v.x, v.y, v.z, v.w};
    float ps = 0.f, pd = 0.f;
    int cb = chunk * 16;
#pragma unroll
    for (int q = 0; q < 4; ++q) {
      f32x2 lo = __builtin_amdgcn_cvt_pk_f32_fp8((int)w[q], false);
      f32x2 hi = __builtin_amdgcn_cvt_pk_f32_fp8((int)w[q], true);
      int c = cb + q * 4;
      ps += lo[0] * a2s[c] + lo[1] * a2s[c + 1] + hi[0] * a2s[c + 2] + hi[1] * a2s[c + 3];
      pd += lo[0] * a2d[c] + lo[1] * a2d[c + 1] + hi[0] * a2d[c + 2] + hi[1] * a2d[c + 3];
    }
    ps += __shfl_xor(ps, 1); pd += __shfl_xor(pd, 1);
    if (chunk == 0 && grow < N) { al2s[grow] = ps; al2d[grow] = pd; }
  }
}

// 8-fp8 (uint2) decode + weighted accumulate, PACKED: f32x2 accumulators so LLVM
// selects v_pk_fma_f32 (double-rate packed f32 FMA on gfx950).
#define DEC8P(HV, EX)                                                       \
  {                                                                         \
    f32x2 _e2; _e2[0] = (EX); _e2[1] = (EX);                                \
    acc01 += __builtin_amdgcn_cvt_pk_f32_fp8((int)(HV).x, false) * _e2;     \
    acc23 += __builtin_amdgcn_cvt_pk_f32_fp8((int)(HV).x, true) * _e2;      \
    acc45 += __builtin_amdgcn_cvt_pk_f32_fp8((int)(HV).y, false) * _e2;     \
    acc67 += __builtin_amdgcn_cvt_pk_f32_fp8((int)(HV).y, true) * _e2;      \
    den += (EX);                                                            \
  }

// ---------------- Layer-1 aggregate v5: depth-1 pipeline (measured best: 51.7-52.1 µs) ----
// Converged: bracketed on pipeline depth (v3=63/v5=52/v6=54.6), VALU content
// (R2-R4 trims), masking (pad=57.2), arbitration (setprio null -> reverted).
__global__ __launch_bounds__(256) void agg1_kernel(
    const int* __restrict__ rowbeg, const int* __restrict__ rowend, const int* __restrict__ csr_src,
    const unsigned char* __restrict__ h1f,  // fp8, [N][128]
    const float* __restrict__ al_s, const float* __restrict__ al_d,
    const float* __restrict__ b1, unsigned* __restrict__ houtb, int N) {
  int t = threadIdx.x;
  int d = (blockIdx.x * 256 + t) >> 6;
  if (d >= N) return;
  int lane = t & 63;
  int e_id = lane >> 4;            // which edge of the 4-edge unit
  unsigned c8 = (unsigned)(lane & 15);  // my 8-col block: cols 8*c8 .. 8*c8+7
  unsigned head = c8 >> 2;
  const unsigned boff = c8 * 8u;   // byte offset within a payload row
  const float ald = al_d[(unsigned)d * 4u + head];
  // d is wave-uniform -> bounds in SGPRs, SALU loop
  const int beg = __builtin_amdgcn_readfirstlane(rowbeg[d]);
  const int end = __builtin_amdgcn_readfirstlane(rowend[d]);
  // prefetch iteration 0's csr entries (in flight across the self-loop compute)
  int idx0 = beg + e_id;
  int idx1 = idx0 + 4;
  int sj0 = (idx0 < end) ? csr_src[(unsigned)idx0] : d;
  int sj1 = (idx1 < end) ? csr_src[(unsigned)idx1] : d;
  f32x2 acc01 = {0.f, 0.f}, acc23 = {0.f, 0.f}, acc45 = {0.f, 0.f}, acc67 = {0.f, 0.f};
  float den = 0.f;
  {  // self loop (counted by e_id==0 only; others multiply by 0)
    float e = al_s[(unsigned)d * 4u + head] + ald;
    e = fmaxf(e, 0.2f * e);
    float ex = (e_id == 0) ? __expf(e) : 0.f;
    uint2 hv = *(const uint2*)(h1f + (((unsigned)d << 7) | boff));
    DEC8P(hv, ex);
  }
  for (int i = beg; i < end; i += 8) {
    const int cidx0 = idx0, cidx1 = idx1;
    const int csj0 = sj0, csj1 = sj1;
    // issue current iteration's dependent loads
    float as0 = al_s[(unsigned)csj0 * 4u + head];
    float as1 = al_s[(unsigned)csj1 * 4u + head];
    uint2 hv0 = *(const uint2*)(h1f + (((unsigned)csj0 << 7) | boff));
    uint2 hv1 = *(const uint2*)(h1f + (((unsigned)csj1 << 7) | boff));
    // prefetch next iteration's csr (branchless; masked lanes don't access memory)
    idx0 += 8; idx1 += 8;
    sj0 = (idx0 < end) ? csr_src[(unsigned)idx0] : d;
    sj1 = (idx1 < end) ? csr_src[(unsigned)idx1] : d;
    // compute current
    float e0 = as0 + ald;
    e0 = fmaxf(e0, 0.2f * e0);
    float ex0 = __expf(e0);
    if (cidx0 >= end) ex0 = 0.f;   // mask tail; loop stays branch-free
    float e1 = as1 + ald;
    e1 = fmaxf(e1, 0.2f * e1);
    float ex1 = __expf(e1);
    if (cidx1 >= end) ex1 = 0.f;
    DEC8P(hv0, ex0);
    DEC8P(hv1, ex1);
  }
  // reduce across the 4 e_id groups (lane bits 4,5); disjoint edge sets, same cols
  float a0 = acc01[0], a1 = acc01[1], a2 = acc23[0], a3 = acc23[1];
  float a4 = acc45[0], a5 = acc45[1], a6 = acc67[0], a7 = acc67[1];
  a0 += __shfl_xor(a0, 16); a1 += __shfl_xor(a1, 16);
  a2 += __shfl_xor(a2, 16); a3 += __shfl_xor(a3, 16);
  a4 += __shfl_xor(a4, 16); a5 += __shfl_xor(a5, 16);
  a6 += __shfl_xor(a6, 16); a7 += __shfl_xor(a7, 16);
  den += __shfl_xor(den, 16);
  a0 += __shfl_xor(a0, 32); a1 += __shfl_xor(a1, 32);
  a2 += __shfl_xor(a2, 32); a3 += __shfl_xor(a3, 32);
  a4 += __shfl_xor(a4, 32); a5 += __shfl_xor(a5, 32);
  a6 += __shfl_xor(a6, 32); a7 += __shfl_xor(a7, 32);
  den += __shfl_xor(den, 32);
  // split epilogue: lane (e_id, c8) finishes output pair (2*e_id, 2*e_id+1)
  float inv = __builtin_amdgcn_rcpf(den);
  float p0 = e_id == 0 ? a0 : e_id == 1 ? a2 : e_id == 2 ? a4 : a6;  // static selects
  float p1 = e_id == 0 ? a1 : e_id == 1 ? a3 : e_id == 2 ? a5 : a7;
  float2 bv = *(const float2*)(b1 + 8 * c8 + 2 * e_id);
  float o0 = p0 * inv + bv.x;
  float o1 = p1 * inv + bv.y;
  // ELU; __expf-1 instead of libm expm1f (error << bf16 output rounding)
  o0 = o0 > 0.f ? o0 : __expf(o0) - 1.f;
  o1 = o1 > 0.f ? o1 : __expf(o1) - 1.f;
  houtb[(unsigned)d * 64u + 4u * c8 + (unsigned)e_id] = cvt_pk_bf16(o0, o1);
}

// ---------------- Layer-2 aggregate v6 + pooled partials (measured neutral-positive) ----
// Quarter-wave per node; depth-2 pipeline; split epilogue + rcp.
__global__ __launch_bounds__(256) void agg2_kernel(
    const int* __restrict__ rowbeg, const int* __restrict__ rowend, const int* __restrict__ csr_src,
    const unsigned char* __restrict__ h2f,  // fp8, [N][32]
    const float* __restrict__ al_s, const float* __restrict__ al_d,
    float* __restrict__ partial, int N) {
  __shared__ float sp[16 * 32];
  int t = threadIdx.x;
  int l16 = t & 15;
  int slot = t >> 4;       // 16 nodes per block
  int node = (blockIdx.x * 256 + t) >> 4;
  int e_id = l16 >> 2;     // which edge of the 4-edge unit
  unsigned c8 = (unsigned)(l16 & 3);  // my 8-col block: cols 8*c8 .. 8*c8+7
  const unsigned boff = c8 * 8u;
  float po0 = 0.f, po1 = 0.f;
  if (node < N) {
    const float ald = al_d[node];
    const int beg = rowbeg[node], end = rowend[node];
    int idx0 = beg + e_id;
    int idx1 = idx0 + 4;
    int sj0 = (idx0 < end) ? csr_src[(unsigned)idx0] : node;
    int sj1 = (idx1 < end) ? csr_src[(unsigned)idx1] : node;
    float self_as = al_s[node];
    uint2 self_hv = *(const uint2*)(h2f + (((unsigned)node << 5) | boff));
    idx0 += 8; idx1 += 8;
    int nsj0 = (idx0 < end) ? csr_src[(unsigned)idx0] : node;
    int nsj1 = (idx1 < end) ? csr_src[(unsigned)idx1] : node;
    float as0 = al_s[(unsigned)sj0];
    float as1 = al_s[(unsigned)sj1];
    uint2 hv0 = *(const uint2*)(h2f + (((unsigned)sj0 << 5) | boff));
    uint2 hv1 = *(const uint2*)(h2f + (((unsigned)sj1 << 5) | boff));
    f32x2 acc01 = {0.f, 0.f}, acc23 = {0.f, 0.f}, acc45 = {0.f, 0.f}, acc67 = {0.f, 0.f};
    float den = 0.f;
    {  // self loop
      float e = self_as + ald;
      e = fmaxf(e, 0.2f * e);
      float ex = (e_id == 0) ? __expf(e) : 0.f;
      DEC8P(self_hv, ex);
    }
    for (int i = beg; i < end; i += 8) {
      idx0 += 8; idx1 += 8;
      int nnsj0 = (idx0 < end) ? csr_src[(unsigned)idx0] : node;
      int nnsj1 = (idx1 < end) ? csr_src[(unsigned)idx1] : node;
      float nas0 = al_s[(unsigned)nsj0];
      float nas1 = al_s[(unsigned)nsj1];
      uint2 nhv0 = *(const uint2*)(h2f + (((unsigned)nsj0 << 5) | boff));
      uint2 nhv1 = *(const uint2*)(h2f + (((unsigned)nsj1 << 5) | boff));
      int cix0 = i + e_id;
      int cix1 = cix0 + 4;
      float e0 = as0 + ald;
      e0 = fmaxf(e0, 0.2f * e0);
      float ex0 = __expf(e0);
      if (cix0 >= end) ex0 = 0.f;
      float e1 = as1 + ald;
      e1 = fmaxf(e1, 0.2f * e1);
      float ex1 = __expf(e1);
      if (cix1 >= end) ex1 = 0.f;
      DEC8P(hv0, ex0);
      DEC8P(hv1, ex1);
      as0 = nas0; as1 = nas1; hv0 = nhv0; hv1 = nhv1;
      nsj0 = nnsj0; nsj1 = nnsj1;
    }
    // reduce across the 4 e_id groups (l16 bits 2,3)
    float a0 = acc01[0], a1 = acc01[1], a2 = acc23[0], a3 = acc23[1];
    float a4 = acc45[0], a5 = acc45[1], a6 = acc67[0], a7 = acc67[1];
    a0 += __shfl_xor(a0, 4); a1 += __shfl_xor(a1, 4);
    a2 += __shfl_xor(a2, 4); a3 += __shfl_xor(a3, 4);
    a4 += __shfl_xor(a4, 4); a5 += __shfl_xor(a5, 4);
    a6 += __shfl_xor(a6, 4); a7 += __shfl_xor(a7, 4);
    den += __shfl_xor(den, 4);
    a0 += __shfl_xor(a0, 8); a1 += __shfl_xor(a1, 8);
    a2 += __shfl_xor(a2, 8); a3 += __shfl_xor(a3, 8);
    a4 += __shfl_xor(a4, 8); a5 += __shfl_xor(a5, 8);
    a6 += __shfl_xor(a6, 8); a7 += __shfl_xor(a7, 8);
    den += __shfl_xor(den, 8);
    float inv = __builtin_amdgcn_rcpf(den);
    float p0 = e_id == 0 ? a0 : e_id == 1 ? a2 : e_id == 2 ? a4 : a6;
    float p1 = e_id == 0 ? a1 : e_id == 1 ? a3 : e_id == 2 ? a5 : a7;
    po0 = p0 * inv; po1 = p1 * inv;
  }
  // every lane writes its pair (covers the node's 32 cols across the 16 lanes)
  *(float2*)&sp[slot * 32 + 8 * c8 + 2 * e_id] = make_float2(po0, po1);
  __syncthreads();
  if (t < 32) {
    float s = 0.f;
#pragma unroll
    for (int j = 0; j < 16; ++j) s += sp[j * 32 + t];
    partial[(size_t)blockIdx.x * 32 + t] = s;
  }
}

// ---------------- reduce stage: partial[nb][32] -> partial2[128][32] ----------------
// (Parallel fold; the R6 single-block fusion was latency-serial at 57 µs.)
__global__ __launch_bounds__(256) void reduce_kernel(
    const float* __restrict__ partial, int nb, float* __restrict__ partial2) {
  __shared__ float sp[8 * 32];
  int t = threadIdx.x;
  int slot = t >> 5, c = t & 31;
  int row0 = blockIdx.x * 8 + slot;
  float s = 0.f;
  for (int i = row0; i < nb; i += 1024) s += partial[(size_t)i * 32 + c];
  sp[slot * 32 + c] = s;
  __syncthreads();
  if (t < 32) {
    float tot = 0.f;
#pragma unroll
    for (int j = 0; j < 8; ++j) tot += sp[j * 32 + t];
    partial2[(size_t)blockIdx.x * 32 + t] = tot;
  }
}

// ---------------- final: pool mean + linear + softmax ----------------
__global__ void final_kernel(const float* __restrict__ partial2, int nb,
                             const float* __restrict__ b2, const float* __restrict__ linW,
                             const float* __restrict__ linb, float* __restrict__ out, int N) {
  __shared__ float sd[256];
  __shared__ float pooled[32];
  int t = threadIdx.x;
  int c = t & 31, g = t >> 5;
  float s = 0.f;
  for (int i = g; i < nb; i += 8) s += partial2[(size_t)i * 32 + c];
  sd[t] = s; __syncthreads();
  if (t < 32) {
    float tot = 0.f;
#pragma unroll
    for (int j = 0; j < 8; ++j) tot += sd[j * 32 + t];
    pooled[t] = tot / (float)N + b2[t];
  }
  __syncthreads();
  if (t == 0) {
    float lg[3];
    for (int j = 0; j < 3; ++j) lg[j] = linb[j];
    for (int cc = 0; cc < 32; ++cc)
      for (int j = 0; j < 3; ++j) lg[j] += pooled[cc] * linW[cc * 3 + j];
    float m = fmaxf(lg[0], fmaxf(lg[1], lg[2]));
    float e0 = __expf(lg[0] - m), e1 = __expf(lg[1] - m), e2 = __expf(lg[2] - m);
    float inv = 1.f / (e0 + e1 + e2);
    out[0] = e0 * inv; out[1] = e1 * inv; out[2] = e2 * inv;
  }
}

extern "C" void kernel_launch(void* const* d_in, const int* in_sizes, int n_in,
                              void* d_out, int out_size, void* d_ws, size_t ws_size,
                              hipStream_t stream) {
  const float* x    = (const float*)d_in[0];
  const void*  eidx = d_in[1];
  const float* W1   = (const float*)d_in[2];
  const float* a1s  = (const float*)d_in[3];
  const float* a1d  = (const float*)d_in[4];
  const float* b1   = (const float*)d_in[5];
  const float* W2   = (const float*)d_in[6];
  const float* a2s  = (const float*)d_in[7];
  const float* a2d  = (const float*)d_in[8];
  const float* b2   = (const float*)d_in[9];
  const float* linW = (const float*)d_in[10];
  const float* linb = (const float*)d_in[11];
  float* out = (float*)d_out;

  const int N = in_sizes[0] / 128;
  const int E = in_sizes[1] / 2;
  const int NB = (N + 127) >> 7;   // 128-node buckets

  char* ws = (char*)d_ws;
  size_t off = 0;
  auto alloc = [&](size_t bytes) -> void* {
    size_t o = off;
    off = align_up(off + bytes, 256);
    return (void*)(ws + o);
  };
  int* cnt    = (int*)alloc((size_t)N * sizeof(int));   // degree counters -> fill pointers
  int* rowbeg = (int*)alloc((size_t)N * sizeof(int));
  int* rowend = (int*)alloc((size_t)N * sizeof(int));
  int* csr    = (int*)alloc((size_t)NB * BCAP * sizeof(int));
  float* al1s = (float*)alloc((size_t)N * 4 * sizeof(float));
  float* al1d = (float*)alloc((size_t)N * 4 * sizeof(float));
  float* al2s = (float*)alloc((size_t)N * sizeof(float));
  float* al2d = (float*)alloc((size_t)N * sizeof(float));
  unsigned short* w1t = (unsigned short*)alloc(16384 * sizeof(unsigned short));
  unsigned short* w2t = (unsigned short*)alloc(4096 * sizeof(unsigned short));
  unsigned char* h1f  = (unsigned char*)alloc((size_t)N * 128);  // fp8 [N][128]
  unsigned* houtb = (unsigned*)alloc((size_t)N * 64 * sizeof(unsigned));  // bf16 ELU'd layer-1 out
  unsigned char* h2f  = (unsigned char*)alloc((size_t)N * 32);   // fp8 [N][32]
  const int nAggBlocks = (N + 15) / 16;
  float* partial  = (float*)alloc((size_t)nAggBlocks * 32 * sizeof(float));
  float* partial2 = (float*)alloc((size_t)128 * 32 * sizeof(float));

  prep_kernel<<<84, 256, 0, stream>>>(W1, W2, w1t, w2t, cnt, N);

  // hist and gemm1 are mutually independent (both need only prep outputs):
  // run them concurrently in one grid. hist uses no LDS -> gemm1's occupancy
  // constraint (52 KB) is unchanged from its standalone form.
  const int NHB = (E + 4095) / 4096;
  const int gemmBlocks = (N + 63) / 64;
  fused_hist_gemm1<<<NHB + gemmBlocks, 256, 0, stream>>>(
      eidx, E, cnt, NHB, x, w1t, a1s, a1d, h1f, al1s, al1d, N);

  buildRow_kernel<<<NB, 128, 0, stream>>>(cnt, rowbeg, rowend, N);
  scatter_kernel<<<(E + 2047) / 2048, 256, 0, stream>>>(eidx, E, cnt, csr);

  agg1_kernel<<<(N * 64 + 255) / 256, 256, 0, stream>>>(
      rowbeg, rowend, csr, h1f, al1s, al1d, b1, houtb, N);
  gemm2_mfma<<<gemmBlocks, 256, 0, stream>>>(houtb, w2t, a2s, a2d, h2f, al2s, al2d, N);
  agg2_kernel<<<(N * 16 + 255) / 256, 256, 0, stream>>>(
      rowbeg, rowend, csr, h2f, al2s, al2d, partial, N);
  reduce_kernel<<<128, 256, 0, stream>>>(partial, nAggBlocks, partial2);
  final_kernel<<<1, 256, 0, stream>>>(partial2, 128, b2, linW, linb, out, N);
}

// Round 12
// 247.919 us; speedup vs baseline: 1.6799x; 1.6799x over previous
//
#include <hip/hip_runtime.h>
#include <cstdint>
#include <cstddef>

static inline size_t align_up(size_t v, size_t a) { return (v + a - 1) & ~(a - 1); }

#define BCAP 3072  // fixed slots per 128-node bucket; mean occupancy 2048, sigma~45 -> +22 sigma margin

typedef __attribute__((ext_vector_type(8))) short short8;
typedef __attribute__((ext_vector_type(4))) float f32x4;
typedef __attribute__((ext_vector_type(2))) float f32x2;

// bf16 helpers (RNE)
__device__ inline unsigned short bf16_1(float x) {
  unsigned u = __float_as_uint(x);
  u += 0x7FFFu + ((u >> 16) & 1u);
  return (unsigned short)(u >> 16);
}
// HW packed cvt: 2 f32 -> 1 uint of 2 bf16 (1 instr vs ~8 for the bit-hack pair).
__device__ inline unsigned cvt_pk_bf16(float lo, float hi) {
  unsigned r;
  asm("v_cvt_pk_bf16_f32 %0, %1, %2" : "=v"(r) : "v"(lo), "v"(hi));
  return r;
}

// fp8 e4m3 (OCP) helpers — HW cvt is RNE (unbiased through mean-pool)
__device__ inline unsigned char fp8_1(float x) {
  return (unsigned char)(__builtin_amdgcn_cvt_pk_fp8_f32(x, x, 0, false) & 0xFF);
}

// ---------------- weight prep: transpose to [c][k] bf16; also zeroes fillB ----------------
__global__ void prep_kernel(const float* __restrict__ W1, const float* __restrict__ W2,
                            unsigned short* __restrict__ w1t, unsigned short* __restrict__ w2t,
                            int* __restrict__ fillB) {
  int t = blockIdx.x * 256 + threadIdx.x;
  if (t < 16384) {
    int c = t >> 7, k = t & 127;
    w1t[t] = bf16_1(W1[(size_t)k * 128 + c]);
  } else if (t < 20480) {
    int i = t - 16384;
    int c = i >> 7, k = i & 127;
    w2t[i] = bf16_1(W2[(size_t)k * 32 + c]);
  } else if (t < 21504) {
    fillB[t - 20480] = 0;   // replaces the hipMemsetAsync dispatch
  }
}

__device__ inline int load_edge(const void* eidx, int is64, size_t idx) {
  if (is64) return (int)((const long long*)eidx)[idx];
  return ((const int*)eidx)[idx];
}

// ======= FUSED sortA ∥ gemm1 (R10 structure, sortA batched 2x) =======
// R11's scatter experiment proved the LDS bucket sort is load-bearing: random 4-B
// scatter writes cost 105 MB of HBM write traffic (16x amplification) vs the
// sort's coalesced segment writes. Kept. This round halves the sort's dominant
// overheads by processing 4096 edges/block (was 2048): reservation atomics on
// fillB halve (~305K over 782 addrs, ~390 contenders/addr vs ~780), and the
// 1024-bucket scan + barrier fixed costs amortize over 2x the edges.
// blocks [0, NBs)           -> sortA body (4096 edges each)
// blocks [NBs, NBs+gemmB)   -> gemm1 body
// Shared LDS: one max-sized buffer (gemm1's 52224 B; sortA uses ~42 KB).

// ---- sortA body: packed entry src | (dst&127)<<20; edges cached in VGPRs across
// the two passes; edge dtype (int64 vs int32) detected per-block from own chunk.
__device__ void sortA_body(char* smem, const void* eidx, int E,
                           int* __restrict__ fillB, unsigned* __restrict__ packed,
                           int NB, int bid) {
  int* hist = (int*)smem;                     // 1024 ints
  int* loff = hist + 1024;                    // 1024
  int* lbase = loff + 1024;                   // 1024
  int* lcnt = lbase + 1024;                   // 1024
  unsigned* sortedV = (unsigned*)(lcnt + 1024);                 // 4096 uints
  unsigned short* sortedB = (unsigned short*)(sortedV + 4096);  // 4096 ushorts
  int* sd = (int*)(sortedB + 4096);           // 256
  int* s_is64 = sd + 256;                     // 1   (total ~41.9 KB)
  const int t = threadIdx.x;
  const int chunk0 = bid * 4096;
  const int cntE = min(4096, E - chunk0);
  if (t == 0) *s_is64 = 1;
  for (int i = t; i < 1024; i += 256) { hist[i] = 0; lcnt[i] = 0; }
  __syncthreads();
  {
    int nchk = min(cntE, 256);
    for (int i = t; i < nchk; i += 256)
      if (((const unsigned*)eidx)[2 * (size_t)(chunk0 + i) + 1] != 0u) *s_is64 = 0;  // benign race
  }
  __syncthreads();
  const int is64 = *s_is64;
  int sv[16], dv[16];
#pragma unroll
  for (int it = 0; it < 16; ++it) {
    int li = it * 256 + t;
    if (li < cntE) {
      sv[it] = load_edge(eidx, is64, (size_t)chunk0 + li);
      dv[it] = load_edge(eidx, is64, (size_t)E + chunk0 + li);
      atomicAdd(&hist[dv[it] >> 7], 1);
    }
  }
  __syncthreads();
  for (int b = t; b < NB; b += 256) {
    int h = hist[b];
    if (h) lbase[b] = b * BCAP + atomicAdd(&fillB[b], h);
  }
  {
    int base = t * 4;
    int v[4]; int s = 0;
#pragma unroll
    for (int j = 0; j < 4; ++j) { v[j] = hist[base + j]; s += v[j]; }
    sd[t] = s; __syncthreads();
    for (int off = 1; off < 256; off <<= 1) {
      int u = (t >= off) ? sd[t - off] : 0;
      __syncthreads();
      sd[t] += u;
      __syncthreads();
    }
    int run = sd[t] - s;
#pragma unroll
    for (int j = 0; j < 4; ++j) { loff[base + j] = run; run += v[j]; }
  }
  __syncthreads();
#pragma unroll
  for (int it = 0; it < 16; ++it) {
    int li = it * 256 + t;
    if (li < cntE) {
      int b = dv[it] >> 7;
      int r = atomicAdd(&lcnt[b], 1);
      int pos = loff[b] + r;
      sortedV[pos] = (unsigned)sv[it] | ((unsigned)(dv[it] & 127) << 20);
      sortedB[pos] = (unsigned short)b;
    }
  }
  __syncthreads();
  for (int li = t; li < cntE; li += 256) {
    int b = sortedB[li];
    packed[(size_t)lbase[b] + (li - loff[b])] = sortedV[li];
  }
}

// ---- gemm1 body (MFMA bf16): h1f = fp8(bf16(x) @ bf16(W1)), + al1 fused
__device__ void gemm1_body(char* smem,
    const float* __restrict__ x, const unsigned short* __restrict__ w1t,
    const float* __restrict__ a1s, const float* __restrict__ a1d,
    unsigned char* __restrict__ h1f, float* __restrict__ al1s, float* __restrict__ al1d,
    int N, int bid) {
  unsigned short* sw = (unsigned short*)smem;    // 128*136
  unsigned short* sx = sw + 128 * 136;           // 64*136; reused as fp8 tile
  unsigned char* ftile = (unsigned char*)sx;
  const int t = threadIdx.x;
  const int row0 = bid * 64;
  for (int i = t; i < 4096; i += 256) {
    int c = i >> 5, k4 = (i & 31) * 4;
    *(ushort4*)&sw[c * 136 + k4] = *(const ushort4*)&w1t[c * 128 + k4];
  }
  for (int i = t; i < 2048; i += 256) {
    int r = i >> 5, c4 = (i & 31) * 4;
    float4 v = make_float4(0.f, 0.f, 0.f, 0.f);
    if (row0 + r < N) v = *(const float4*)(x + (size_t)(row0 + r) * 128 + c4);
    uint2 b;                       // packed HW cvt: 2 instrs for 4 values
    b.x = cvt_pk_bf16(v.x, v.y);
    b.y = cvt_pk_bf16(v.z, v.w);
    *(uint2*)&sx[r * 136 + c4] = b;
  }
  __syncthreads();
  const int lane = t & 63, wave = t >> 6;
  const int m = lane & 15, quad = lane >> 4;
  const unsigned short* arow = &sx[(wave * 16 + m) * 136];
  short8 A[4];
#pragma unroll
  for (int ks = 0; ks < 4; ++ks) A[ks] = *(const short8*)&arow[ks * 32 + quad * 8];
  __syncthreads();  // all waves have A in regs; sx region now writable as fp8 tile
  const int lrow = wave * 16 + quad * 4;
#pragma unroll
  for (int nt = 0; nt < 8; ++nt) {
    const unsigned short* brow = &sw[(nt * 16 + m) * 136];
    f32x4 acc = {0.f, 0.f, 0.f, 0.f};
#pragma unroll
    for (int ks = 0; ks < 4; ++ks) {
      short8 B = *(const short8*)&brow[ks * 32 + quad * 8];
      acc = __builtin_amdgcn_mfma_f32_16x16x32_bf16(A[ks], B, acc, 0, 0, 0);
    }
#pragma unroll
    for (int r = 0; r < 4; ++r)
      ftile[(lrow + r) * 128 + nt * 16 + m] = fp8_1(acc[r]);
  }
  __syncthreads();
  // coalesced flush + fused al1 (from the same fp8 values the gather will see)
#pragma unroll
  for (int it = 0; it < 2; ++it) {
    int row = it * 32 + (t >> 3);
    int chunk = t & 7;            // 16-byte chunk = 16 cols; head = chunk>>1
    uint4 v = *(const uint4*)&ftile[row * 128 + chunk * 16];
    int grow = row0 + row;
    if (grow < N) *(uint4*)&h1f[(size_t)grow * 128 + chunk * 16] = v;
    unsigned w[4] = {v.x, v.y, v.z, v.w};
    float ps = 0.f, pd = 0.f;
    int cb = chunk * 16;
#pragma unroll
    for (int q = 0; q < 4; ++q) {
      f32x2 lo = __builtin_amdgcn_cvt_pk_f32_fp8((int)w[q], false);
      f32x2 hi = __builtin_amdgcn_cvt_pk_f32_fp8((int)w[q], true);
      int c = cb + q * 4;
      ps += lo[0] * a1s[c] + lo[1] * a1s[c + 1] + hi[0] * a1s[c + 2] + hi[1] * a1s[c + 3];
      pd += lo[0] * a1d[c] + lo[1] * a1d[c + 1] + hi[0] * a1d[c + 2] + hi[1] * a1d[c + 3];
    }
    ps += __shfl_xor(ps, 1); pd += __shfl_xor(pd, 1);  // pair chunks c, c^1 -> full head
    if ((chunk & 1) == 0 && grow < N) {
      int head = chunk >> 1;
      al1s[(size_t)grow * 4 + head] = ps;
      al1d[(size_t)grow * 4 + head] = pd;
    }
  }
}

__global__ __launch_bounds__(256) void fused_sort_gemm1(
    const void* eidx, int E, int* __restrict__ fillB, unsigned* __restrict__ packed,
    int NB, int NBs,
    const float* __restrict__ x, const unsigned short* __restrict__ w1t,
    const float* __restrict__ a1s, const float* __restrict__ a1d,
    unsigned char* __restrict__ h1f, float* __restrict__ al1s, float* __restrict__ al1d,
    int N) {
  __shared__ __align__(16) char smem[52224];   // max(sortA ~41.9 KB, gemm1 52224 B)
  int bid = blockIdx.x;
  if (bid < NBs) {
    sortA_body(smem, eidx, E, fillB, packed, NB, bid);
  } else {
    gemm1_body(smem, x, w1t, a1s, a1d, h1f, al1s, al1d, N, bid - NBs);
  }
}

__global__ __launch_bounds__(256) void buildCSR_kernel(const unsigned* __restrict__ packed,
                                                       const int* __restrict__ fillB,
                                                       int* __restrict__ rowbeg,
                                                       int* __restrict__ rowend,
                                                       int* __restrict__ csr, int N, int NB) {
  __shared__ int cnt[128], ex[128], fill[128];
  const int b = blockIdx.x;
  const int t = threadIdx.x;
  const int beg = b * BCAP;
  const int end = beg + fillB[b];
  const int node0 = b << 7;
  const int nn = min(128, N - node0);
  if (t < 128) { cnt[t] = 0; fill[t] = 0; }
  __syncthreads();
  for (int i = beg + t; i < end; i += 256) {
    int j = (packed[i] >> 20) & 127;
    atomicAdd(&cnt[j], 1);
  }
  __syncthreads();
  if (t < 128) ex[t] = cnt[t];
  __syncthreads();
  for (int off = 1; off < 128; off <<= 1) {
    int u = (t >= off && t < 128) ? ex[t - off] : 0;
    __syncthreads();
    if (t < 128) ex[t] += u;
    __syncthreads();
  }
  if (t < 128) ex[t] -= cnt[t];  // exclusive
  __syncthreads();
  if (t < nn) {
    rowbeg[node0 + t] = beg + ex[t];
    rowend[node0 + t] = beg + ex[t] + cnt[t];
  }
  for (int i = beg + t; i < end; i += 256) {
    unsigned v = packed[i];
    int j = (v >> 20) & 127;
    int r = atomicAdd(&fill[j], 1);
    csr[beg + ex[j] + r] = (int)(v & 0xFFFFFu);
  }
}

// ---------------- GEMM2 (MFMA bf16): h2f = fp8(houtb @ bf16(W2)), + al2 fused ----------------
__global__ __launch_bounds__(256) void gemm2_mfma(
    const unsigned* __restrict__ houtb, const unsigned short* __restrict__ w2t,
    const float* __restrict__ a2s, const float* __restrict__ a2d,
    unsigned char* __restrict__ h2f, float* __restrict__ al2s, float* __restrict__ al2d, int N) {
  __shared__ unsigned short sw[32 * 136];
  __shared__ unsigned short sx[64 * 136];
  unsigned char* ftile = (unsigned char*)sx;  // 2 KB fp8 tile
  const int t = threadIdx.x;
  const int row0 = blockIdx.x * 64;
  for (int i = t; i < 1024; i += 256) {
    int c = i >> 5, k4 = (i & 31) * 4;
    *(ushort4*)&sw[c * 136 + k4] = *(const ushort4*)&w2t[c * 128 + k4];
  }
  for (int i = t; i < 2048; i += 256) {
    int r = i >> 5, d2 = (i & 31) * 2;
    uint2 v = make_uint2(0u, 0u);
    if (row0 + r < N) v = *(const uint2*)(houtb + (size_t)(row0 + r) * 64 + d2);
    *(uint2*)&sx[r * 136 + d2 * 2] = v;
  }
  __syncthreads();
  const int lane = t & 63, wave = t >> 6;
  const int m = lane & 15, quad = lane >> 4;
  const unsigned short* arow = &sx[(wave * 16 + m) * 136];
  short8 A[4];
#pragma unroll
  for (int ks = 0; ks < 4; ++ks) A[ks] = *(const short8*)&arow[ks * 32 + quad * 8];
  __syncthreads();
  const int lrow = wave * 16 + quad * 4;
#pragma unroll
  for (int nt = 0; nt < 2; ++nt) {
    const unsigned short* brow = &sw[(nt * 16 + m) * 136];
    f32x4 acc = {0.f, 0.f, 0.f, 0.f};
#pragma unroll
    for (int ks = 0; ks < 4; ++ks) {
      short8 B = *(const short8*)&brow[ks * 32 + quad * 8];
      acc = __builtin_amdgcn_mfma_f32_16x16x32_bf16(A[ks], B, acc, 0, 0, 0);
    }
#pragma unroll
    for (int r = 0; r < 4; ++r)
      ftile[(lrow + r) * 32 + nt * 16 + m] = fp8_1(acc[r]);
  }
  __syncthreads();
  if (t < 128) {
    int row = t >> 1, chunk = t & 1;  // 16-byte chunk = 16 of 32 cols
    uint4 v = *(const uint4*)&ftile[row * 32 + chunk * 16];
    int grow = row0 + row;
    if (grow < N) *(uint4*)&h2f[(size_t)grow * 32 + chunk * 16] = v;
    unsigned w[4] = {v.x, v.y, v.z, v.w};
    float ps = 0.f, pd = 0.f;
    int cb = chunk * 16;
#pragma unroll
    for (int q = 0; q < 4; ++q) {
      f32x2 lo = __builtin_amdgcn_cvt_pk_f32_fp8((int)w[q], false);
      f32x2 hi = __builtin_amdgcn_cvt_pk_f32_fp8((int)w[q], true);
      int c = cb + q * 4;
      ps += lo[0] * a2s[c] + lo[1] * a2s[c + 1] + hi[0] * a2s[c + 2] + hi[1] * a2s[c + 3];
      pd += lo[0] * a2d[c] + lo[1] * a2d[c + 1] + hi[0] * a2d[c + 2] + hi[1] * a2d[c + 3];
    }
    ps += __shfl_xor(ps, 1); pd += __shfl_xor(pd, 1);
    if (chunk == 0 && grow < N) { al2s[grow] = ps; al2d[grow] = pd; }
  }
}

// 8-fp8 (uint2) decode + weighted accumulate, PACKED: f32x2 accumulators so LLVM
// selects v_pk_fma_f32 (double-rate packed f32 FMA on gfx950).
#define DEC8P(HV, EX)                                                       \
  {                                                                         \
    f32x2 _e2; _e2[0] = (EX); _e2[1] = (EX);                                \
    acc01 += __builtin_amdgcn_cvt_pk_f32_fp8((int)(HV).x, false) * _e2;     \
    acc23 += __builtin_amdgcn_cvt_pk_f32_fp8((int)(HV).x, true) * _e2;      \
    acc45 += __builtin_amdgcn_cvt_pk_f32_fp8((int)(HV).y, false) * _e2;     \
    acc67 += __builtin_amdgcn_cvt_pk_f32_fp8((int)(HV).y, true) * _e2;      \
    den += (EX);                                                            \
  }

// ---------------- Layer-1 aggregate v5: depth-1 pipeline (measured best: 51.7-52.1 µs) ----
// Converged: bracketed on pipeline depth (v3=63/v5=52/v6=54.6), VALU content
// (R2-R4 trims), masking (pad=57.2), arbitration (setprio null -> reverted).
__global__ __launch_bounds__(256) void agg1_kernel(
    const int* __restrict__ rowbeg, const int* __restrict__ rowend, const int* __restrict__ csr_src,
    const unsigned char* __restrict__ h1f,  // fp8, [N][128]
    const float* __restrict__ al_s, const float* __restrict__ al_d,
    const float* __restrict__ b1, unsigned* __restrict__ houtb, int N) {
  int t = threadIdx.x;
  int d = (blockIdx.x * 256 + t) >> 6;
  if (d >= N) return;
  int lane = t & 63;
  int e_id = lane >> 4;            // which edge of the 4-edge unit
  unsigned c8 = (unsigned)(lane & 15);  // my 8-col block: cols 8*c8 .. 8*c8+7
  unsigned head = c8 >> 2;
  const unsigned boff = c8 * 8u;   // byte offset within a payload row
  const float ald = al_d[(unsigned)d * 4u + head];
  // d is wave-uniform -> bounds in SGPRs, SALU loop
  const int beg = __builtin_amdgcn_readfirstlane(rowbeg[d]);
  const int end = __builtin_amdgcn_readfirstlane(rowend[d]);
  // prefetch iteration 0's csr entries (in flight across the self-loop compute)
  int idx0 = beg + e_id;
  int idx1 = idx0 + 4;
  int sj0 = (idx0 < end) ? csr_src[(unsigned)idx0] : d;
  int sj1 = (idx1 < end) ? csr_src[(unsigned)idx1] : d;
  f32x2 acc01 = {0.f, 0.f}, acc23 = {0.f, 0.f}, acc45 = {0.f, 0.f}, acc67 = {0.f, 0.f};
  float den = 0.f;
  {  // self loop (counted by e_id==0 only; others multiply by 0)
    float e = al_s[(unsigned)d * 4u + head] + ald;
    e = fmaxf(e, 0.2f * e);
    float ex = (e_id == 0) ? __expf(e) : 0.f;
    uint2 hv = *(const uint2*)(h1f + (((unsigned)d << 7) | boff));
    DEC8P(hv, ex);
  }
  for (int i = beg; i < end; i += 8) {
    const int cidx0 = idx0, cidx1 = idx1;
    const int csj0 = sj0, csj1 = sj1;
    // issue current iteration's dependent loads
    float as0 = al_s[(unsigned)csj0 * 4u + head];
    float as1 = al_s[(unsigned)csj1 * 4u + head];
    uint2 hv0 = *(const uint2*)(h1f + (((unsigned)csj0 << 7) | boff));
    uint2 hv1 = *(const uint2*)(h1f + (((unsigned)csj1 << 7) | boff));
    // prefetch next iteration's csr (branchless; masked lanes don't access memory)
    idx0 += 8; idx1 += 8;
    sj0 = (idx0 < end) ? csr_src[(unsigned)idx0] : d;
    sj1 = (idx1 < end) ? csr_src[(unsigned)idx1] : d;
    // compute current
    float e0 = as0 + ald;
    e0 = fmaxf(e0, 0.2f * e0);
    float ex0 = __expf(e0);
    if (cidx0 >= end) ex0 = 0.f;   // mask tail; loop stays branch-free
    float e1 = as1 + ald;
    e1 = fmaxf(e1, 0.2f * e1);
    float ex1 = __expf(e1);
    if (cidx1 >= end) ex1 = 0.f;
    DEC8P(hv0, ex0);
    DEC8P(hv1, ex1);
  }
  // reduce across the 4 e_id groups (lane bits 4,5); disjoint edge sets, same cols
  float a0 = acc01[0], a1 = acc01[1], a2 = acc23[0], a3 = acc23[1];
  float a4 = acc45[0], a5 = acc45[1], a6 = acc67[0], a7 = acc67[1];
  a0 += __shfl_xor(a0, 16); a1 += __shfl_xor(a1, 16);
  a2 += __shfl_xor(a2, 16); a3 += __shfl_xor(a3, 16);
  a4 += __shfl_xor(a4, 16); a5 += __shfl_xor(a5, 16);
  a6 += __shfl_xor(a6, 16); a7 += __shfl_xor(a7, 16);
  den += __shfl_xor(den, 16);
  a0 += __shfl_xor(a0, 32); a1 += __shfl_xor(a1, 32);
  a2 += __shfl_xor(a2, 32); a3 += __shfl_xor(a3, 32);
  a4 += __shfl_xor(a4, 32); a5 += __shfl_xor(a5, 32);
  a6 += __shfl_xor(a6, 32); a7 += __shfl_xor(a7, 32);
  den += __shfl_xor(den, 32);
  // split epilogue: lane (e_id, c8) finishes output pair (2*e_id, 2*e_id+1)
  float inv = __builtin_amdgcn_rcpf(den);
  float p0 = e_id == 0 ? a0 : e_id == 1 ? a2 : e_id == 2 ? a4 : a6;  // static selects
  float p1 = e_id == 0 ? a1 : e_id == 1 ? a3 : e_id == 2 ? a5 : a7;
  float2 bv = *(const float2*)(b1 + 8 * c8 + 2 * e_id);
  float o0 = p0 * inv + bv.x;
  float o1 = p1 * inv + bv.y;
  // ELU; __expf-1 instead of libm expm1f (error << bf16 output rounding)
  o0 = o0 > 0.f ? o0 : __expf(o0) - 1.f;
  o1 = o1 > 0.f ? o1 : __expf(o1) - 1.f;
  houtb[(unsigned)d * 64u + 4u * c8 + (unsigned)e_id] = cvt_pk_bf16(o0, o1);
}

// ---------------- Layer-2 aggregate v6 + pooled partials (measured neutral-positive) ----
// Quarter-wave per node; depth-2 pipeline; split epilogue + rcp.
__global__ __launch_bounds__(256) void agg2_kernel(
    const int* __restrict__ rowbeg, const int* __restrict__ rowend, const int* __restrict__ csr_src,
    const unsigned char* __restrict__ h2f,  // fp8, [N][32]
    const float* __restrict__ al_s, const float* __restrict__ al_d,
    float* __restrict__ partial, int N) {
  __shared__ float sp[16 * 32];
  int t = threadIdx.x;
  int l16 = t & 15;
  int slot = t >> 4;       // 16 nodes per block
  int node = (blockIdx.x * 256 + t) >> 4;
  int e_id = l16 >> 2;     // which edge of the 4-edge unit
  unsigned c8 = (unsigned)(l16 & 3);  // my 8-col block: cols 8*c8 .. 8*c8+7
  const unsigned boff = c8 * 8u;
  float po0 = 0.f, po1 = 0.f;
  if (node < N) {
    const float ald = al_d[node];
    const int beg = rowbeg[node], end = rowend[node];
    int idx0 = beg + e_id;
    int idx1 = idx0 + 4;
    int sj0 = (idx0 < end) ? csr_src[(unsigned)idx0] : node;
    int sj1 = (idx1 < end) ? csr_src[(unsigned)idx1] : node;
    float self_as = al_s[node];
    uint2 self_hv = *(const uint2*)(h2f + (((unsigned)node << 5) | boff));
    idx0 += 8; idx1 += 8;
    int nsj0 = (idx0 < end) ? csr_src[(unsigned)idx0] : node;
    int nsj1 = (idx1 < end) ? csr_src[(unsigned)idx1] : node;
    float as0 = al_s[(unsigned)sj0];
    float as1 = al_s[(unsigned)sj1];
    uint2 hv0 = *(const uint2*)(h2f + (((unsigned)sj0 << 5) | boff));
    uint2 hv1 = *(const uint2*)(h2f + (((unsigned)sj1 << 5) | boff));
    f32x2 acc01 = {0.f, 0.f}, acc23 = {0.f, 0.f}, acc45 = {0.f, 0.f}, acc67 = {0.f, 0.f};
    float den = 0.f;
    {  // self loop
      float e = self_as + ald;
      e = fmaxf(e, 0.2f * e);
      float ex = (e_id == 0) ? __expf(e) : 0.f;
      DEC8P(self_hv, ex);
    }
    for (int i = beg; i < end; i += 8) {
      idx0 += 8; idx1 += 8;
      int nnsj0 = (idx0 < end) ? csr_src[(unsigned)idx0] : node;
      int nnsj1 = (idx1 < end) ? csr_src[(unsigned)idx1] : node;
      float nas0 = al_s[(unsigned)nsj0];
      float nas1 = al_s[(unsigned)nsj1];
      uint2 nhv0 = *(const uint2*)(h2f + (((unsigned)nsj0 << 5) | boff));
      uint2 nhv1 = *(const uint2*)(h2f + (((unsigned)nsj1 << 5) | boff));
      int cix0 = i + e_id;
      int cix1 = cix0 + 4;
      float e0 = as0 + ald;
      e0 = fmaxf(e0, 0.2f * e0);
      float ex0 = __expf(e0);
      if (cix0 >= end) ex0 = 0.f;
      float e1 = as1 + ald;
      e1 = fmaxf(e1, 0.2f * e1);
      float ex1 = __expf(e1);
      if (cix1 >= end) ex1 = 0.f;
      DEC8P(hv0, ex0);
      DEC8P(hv1, ex1);
      as0 = nas0; as1 = nas1; hv0 = nhv0; hv1 = nhv1;
      nsj0 = nnsj0; nsj1 = nnsj1;
    }
    // reduce across the 4 e_id groups (l16 bits 2,3)
    float a0 = acc01[0], a1 = acc01[1], a2 = acc23[0], a3 = acc23[1];
    float a4 = acc45[0], a5 = acc45[1], a6 = acc67[0], a7 = acc67[1];
    a0 += __shfl_xor(a0, 4); a1 += __shfl_xor(a1, 4);
    a2 += __shfl_xor(a2, 4); a3 += __shfl_xor(a3, 4);
    a4 += __shfl_xor(a4, 4); a5 += __shfl_xor(a5, 4);
    a6 += __shfl_xor(a6, 4); a7 += __shfl_xor(a7, 4);
    den += __shfl_xor(den, 4);
    a0 += __shfl_xor(a0, 8); a1 += __shfl_xor(a1, 8);
    a2 += __shfl_xor(a2, 8); a3 += __shfl_xor(a3, 8);
    a4 += __shfl_xor(a4, 8); a5 += __shfl_xor(a5, 8);
    a6 += __shfl_xor(a6, 8); a7 += __shfl_xor(a7, 8);
    den += __shfl_xor(den, 8);
    float inv = __builtin_amdgcn_rcpf(den);
    float p0 = e_id == 0 ? a0 : e_id == 1 ? a2 : e_id == 2 ? a4 : a6;
    float p1 = e_id == 0 ? a1 : e_id == 1 ? a3 : e_id == 2 ? a5 : a7;
    po0 = p0 * inv; po1 = p1 * inv;
  }
  // every lane writes its pair (covers the node's 32 cols across the 16 lanes)
  *(float2*)&sp[slot * 32 + 8 * c8 + 2 * e_id] = make_float2(po0, po1);
  __syncthreads();
  if (t < 32) {
    float s = 0.f;
#pragma unroll
    for (int j = 0; j < 16; ++j) s += sp[j * 32 + t];
    partial[(size_t)blockIdx.x * 32 + t] = s;
  }
}

// ---------------- reduce stage: partial[nb][32] -> partial2[128][32] ----------------
// (Parallel fold; the R6 single-block fusion was latency-serial at 57 µs.)
__global__ __launch_bounds__(256) void reduce_kernel(
    const float* __restrict__ partial, int nb, float* __restrict__ partial2) {
  __shared__ float sp[8 * 32];
  int t = threadIdx.x;
  int slot = t >> 5, c = t & 31;
  int row0 = blockIdx.x * 8 + slot;
  float s = 0.f;
  for (int i = row0; i < nb; i += 1024) s += partial[(size_t)i * 32 + c];
  sp[slot * 32 + c] = s;
  __syncthreads();
  if (t < 32) {
    float tot = 0.f;
#pragma unroll
    for (int j = 0; j < 8; ++j) tot += sp[j * 32 + t];
    partial2[(size_t)blockIdx.x * 32 + t] = tot;
  }
}

// ---------------- final: pool mean + linear + softmax ----------------
__global__ void final_kernel(const float* __restrict__ partial2, int nb,
                             const float* __restrict__ b2, const float* __restrict__ linW,
                             const float* __restrict__ linb, float* __restrict__ out, int N) {
  __shared__ float sd[256];
  __shared__ float pooled[32];
  int t = threadIdx.x;
  int c = t & 31, g = t >> 5;
  float s = 0.f;
  for (int i = g; i < nb; i += 8) s += partial2[(size_t)i * 32 + c];
  sd[t] = s; __syncthreads();
  if (t < 32) {
    float tot = 0.f;
#pragma unroll
    for (int j = 0; j < 8; ++j) tot += sd[j * 32 + t];
    pooled[t] = tot / (float)N + b2[t];
  }
  __syncthreads();
  if (t == 0) {
    float lg[3];
    for (int j = 0; j < 3; ++j) lg[j] = linb[j];
    for (int cc = 0; cc < 32; ++cc)
      for (int j = 0; j < 3; ++j) lg[j] += pooled[cc] * linW[cc * 3 + j];
    float m = fmaxf(lg[0], fmaxf(lg[1], lg[2]));
    float e0 = __expf(lg[0] - m), e1 = __expf(lg[1] - m), e2 = __expf(lg[2] - m);
    float inv = 1.f / (e0 + e1 + e2);
    out[0] = e0 * inv; out[1] = e1 * inv; out[2] = e2 * inv;
  }
}

extern "C" void kernel_launch(void* const* d_in, const int* in_sizes, int n_in,
                              void* d_out, int out_size, void* d_ws, size_t ws_size,
                              hipStream_t stream) {
  const float* x    = (const float*)d_in[0];
  const void*  eidx = d_in[1];
  const float* W1   = (const float*)d_in[2];
  const float* a1s  = (const float*)d_in[3];
  const float* a1d  = (const float*)d_in[4];
  const float* b1   = (const float*)d_in[5];
  const float* W2   = (const float*)d_in[6];
  const float* a2s  = (const float*)d_in[7];
  const float* a2d  = (const float*)d_in[8];
  const float* b2   = (const float*)d_in[9];
  const float* linW = (const float*)d_in[10];
  const float* linb = (const float*)d_in[11];
  float* out = (float*)d_out;

  const int N = in_sizes[0] / 128;
  const int E = in_sizes[1] / 2;
  const int NB = (N + 127) >> 7;   // 128-node buckets; must be <= 1024

  char* ws = (char*)d_ws;
  size_t off = 0;
  auto alloc = [&](size_t bytes) -> void* {
    size_t o = off;
    off = align_up(off + bytes, 256);
    return (void*)(ws + o);
  };
  int* fillB  = (int*)alloc((size_t)1024 * sizeof(int));
  int* rowbeg = (int*)alloc((size_t)N * sizeof(int));
  int* rowend = (int*)alloc((size_t)N * sizeof(int));
  unsigned* packed = (unsigned*)alloc((size_t)NB * BCAP * sizeof(unsigned));
  int* csr    = (int*)alloc((size_t)NB * BCAP * sizeof(int));
  float* al1s = (float*)alloc((size_t)N * 4 * sizeof(float));
  float* al1d = (float*)alloc((size_t)N * 4 * sizeof(float));
  float* al2s = (float*)alloc((size_t)N * sizeof(float));
  float* al2d = (float*)alloc((size_t)N * sizeof(float));
  unsigned short* w1t = (unsigned short*)alloc(16384 * sizeof(unsigned short));
  unsigned short* w2t = (unsigned short*)alloc(4096 * sizeof(unsigned short));
  unsigned char* h1f  = (unsigned char*)alloc((size_t)N * 128);  // fp8 [N][128]
  unsigned* houtb = (unsigned*)alloc((size_t)N * 64 * sizeof(unsigned));  // bf16 ELU'd layer-1 out
  unsigned char* h2f  = (unsigned char*)alloc((size_t)N * 32);   // fp8 [N][32]
  const int nAggBlocks = (N + 15) / 16;
  float* partial  = (float*)alloc((size_t)nAggBlocks * 32 * sizeof(float));
  float* partial2 = (float*)alloc((size_t)128 * 32 * sizeof(float));

  prep_kernel<<<84, 256, 0, stream>>>(W1, W2, w1t, w2t, fillB);

  // sortA and gemm1 are mutually independent (both need only prep outputs):
  // run them concurrently in one grid. sortA batched at 4096 edges/block.
  const int NBs = (E + 4095) / 4096;
  const int gemmBlocks = (N + 63) / 64;
  fused_sort_gemm1<<<NBs + gemmBlocks, 256, 0, stream>>>(
      eidx, E, fillB, packed, NB, NBs, x, w1t, a1s, a1d, h1f, al1s, al1d, N);

  buildCSR_kernel<<<NB, 256, 0, stream>>>(packed, fillB, rowbeg, rowend, csr, N, NB);
  agg1_kernel<<<(N * 64 + 255) / 256, 256, 0, stream>>>(
      rowbeg, rowend, csr, h1f, al1s, al1d, b1, houtb, N);
  gemm2_mfma<<<gemmBlocks, 256, 0, stream>>>(houtb, w2t, a2s, a2d, h2f, al2s, al2d, N);
  agg2_kernel<<<(N * 16 + 255) / 256, 256, 0, stream>>>(
      rowbeg, rowend, csr, h2f, al2s, al2d, partial, N);
  reduce_kernel<<<128, 256, 0, stream>>>(partial, nAggBlocks, partial2);
  final_kernel<<<1, 256, 0, stream>>>(partial2, 128, b2, linW, linb, out, N);
}

// Round 13
// 242.778 us; speedup vs baseline: 1.7155x; 1.0212x over previous
//
#include <hip/hip_runtime.h>
#include <cstdint>
#include <cstddef>

static inline size_t align_up(size_t v, size_t a) { return (v + a - 1) & ~(a - 1); }

#define BCAP 3072  // fixed slots per 128-node bucket; mean occupancy 2048, sigma~45 -> +22 sigma margin

typedef __attribute__((ext_vector_type(8))) short short8;
typedef __attribute__((ext_vector_type(4))) float f32x4;
typedef __attribute__((ext_vector_type(2))) float f32x2;

// bf16 helpers (RNE)
__device__ inline unsigned short bf16_1(float x) {
  unsigned u = __float_as_uint(x);
  u += 0x7FFFu + ((u >> 16) & 1u);
  return (unsigned short)(u >> 16);
}
// HW packed cvt: 2 f32 -> 1 uint of 2 bf16 (1 instr vs ~8 for the bit-hack pair).
__device__ inline unsigned cvt_pk_bf16(float lo, float hi) {
  unsigned r;
  asm("v_cvt_pk_bf16_f32 %0, %1, %2" : "=v"(r) : "v"(lo), "v"(hi));
  return r;
}

// fp8 e4m3 (OCP) helpers — HW cvt is RNE (unbiased through mean-pool)
__device__ inline unsigned char fp8_1(float x) {
  return (unsigned char)(__builtin_amdgcn_cvt_pk_fp8_f32(x, x, 0, false) & 0xFF);
}

// ---------------- weight prep: transpose to [c][k] bf16; also zeroes fillB ----------------
__global__ void prep_kernel(const float* __restrict__ W1, const float* __restrict__ W2,
                            unsigned short* __restrict__ w1t, unsigned short* __restrict__ w2t,
                            int* __restrict__ fillB) {
  int t = blockIdx.x * 256 + threadIdx.x;
  if (t < 16384) {
    int c = t >> 7, k = t & 127;
    w1t[t] = bf16_1(W1[(size_t)k * 128 + c]);
  } else if (t < 20480) {
    int i = t - 16384;
    int c = i >> 7, k = i & 127;
    w2t[i] = bf16_1(W2[(size_t)k * 32 + c]);
  } else if (t < 21504) {
    fillB[t - 20480] = 0;   // replaces the hipMemsetAsync dispatch
  }
}

__device__ inline int load_edge(const void* eidx, int is64, size_t idx) {
  if (is64) return (int)((const long long*)eidx)[idx];
  return ((const int*)eidx)[idx];
}

// ======= FUSED sortA ∥ gemm1 (R12 structure: sortA batched at 4096 edges/block) =======
// R11's scatter experiment proved the LDS bucket sort is load-bearing (random 4-B
// scatter = 105 MB write traffic, 16x amplification). R12's 2x batching cut the
// fused kernel 74 -> 56.7 µs (reservation atomics + scan fixed costs halved).
// Further batching (6144) would push LDS past gemm1's 52.2 KB -> occupancy 3->2
// blocks/CU — not taken.

// ---- sortA body: packed entry src | (dst&127)<<20; edges cached in VGPRs across
// the two passes; edge dtype (int64 vs int32) detected per-block from own chunk.
__device__ void sortA_body(char* smem, const void* eidx, int E,
                           int* __restrict__ fillB, unsigned* __restrict__ packed,
                           int NB, int bid) {
  int* hist = (int*)smem;                     // 1024 ints
  int* loff = hist + 1024;                    // 1024
  int* lbase = loff + 1024;                   // 1024
  int* lcnt = lbase + 1024;                   // 1024
  unsigned* sortedV = (unsigned*)(lcnt + 1024);                 // 4096 uints
  unsigned short* sortedB = (unsigned short*)(sortedV + 4096);  // 4096 ushorts
  int* sd = (int*)(sortedB + 4096);           // 256
  int* s_is64 = sd + 256;                     // 1   (total ~41.9 KB)
  const int t = threadIdx.x;
  const int chunk0 = bid * 4096;
  const int cntE = min(4096, E - chunk0);
  if (t == 0) *s_is64 = 1;
  for (int i = t; i < 1024; i += 256) { hist[i] = 0; lcnt[i] = 0; }
  __syncthreads();
  {
    int nchk = min(cntE, 256);
    for (int i = t; i < nchk; i += 256)
      if (((const unsigned*)eidx)[2 * (size_t)(chunk0 + i) + 1] != 0u) *s_is64 = 0;  // benign race
  }
  __syncthreads();
  const int is64 = *s_is64;
  int sv[16], dv[16];
#pragma unroll
  for (int it = 0; it < 16; ++it) {
    int li = it * 256 + t;
    if (li < cntE) {
      sv[it] = load_edge(eidx, is64, (size_t)chunk0 + li);
      dv[it] = load_edge(eidx, is64, (size_t)E + chunk0 + li);
      atomicAdd(&hist[dv[it] >> 7], 1);
    }
  }
  __syncthreads();
  for (int b = t; b < NB; b += 256) {
    int h = hist[b];
    if (h) lbase[b] = b * BCAP + atomicAdd(&fillB[b], h);
  }
  {
    int base = t * 4;
    int v[4]; int s = 0;
#pragma unroll
    for (int j = 0; j < 4; ++j) { v[j] = hist[base + j]; s += v[j]; }
    sd[t] = s; __syncthreads();
    for (int off = 1; off < 256; off <<= 1) {
      int u = (t >= off) ? sd[t - off] : 0;
      __syncthreads();
      sd[t] += u;
      __syncthreads();
    }
    int run = sd[t] - s;
#pragma unroll
    for (int j = 0; j < 4; ++j) { loff[base + j] = run; run += v[j]; }
  }
  __syncthreads();
#pragma unroll
  for (int it = 0; it < 16; ++it) {
    int li = it * 256 + t;
    if (li < cntE) {
      int b = dv[it] >> 7;
      int r = atomicAdd(&lcnt[b], 1);
      int pos = loff[b] + r;
      sortedV[pos] = (unsigned)sv[it] | ((unsigned)(dv[it] & 127) << 20);
      sortedB[pos] = (unsigned short)b;
    }
  }
  __syncthreads();
  for (int li = t; li < cntE; li += 256) {
    int b = sortedB[li];
    packed[(size_t)lbase[b] + (li - loff[b])] = sortedV[li];
  }
}

// ---- gemm1 body (MFMA bf16): h1f = fp8(bf16(x) @ bf16(W1)), + al1 fused
__device__ void gemm1_body(char* smem,
    const float* __restrict__ x, const unsigned short* __restrict__ w1t,
    const float* __restrict__ a1s, const float* __restrict__ a1d,
    unsigned char* __restrict__ h1f, float* __restrict__ al1s, float* __restrict__ al1d,
    int N, int bid) {
  unsigned short* sw = (unsigned short*)smem;    // 128*136
  unsigned short* sx = sw + 128 * 136;           // 64*136; reused as fp8 tile
  unsigned char* ftile = (unsigned char*)sx;
  const int t = threadIdx.x;
  const int row0 = bid * 64;
  for (int i = t; i < 4096; i += 256) {
    int c = i >> 5, k4 = (i & 31) * 4;
    *(ushort4*)&sw[c * 136 + k4] = *(const ushort4*)&w1t[c * 128 + k4];
  }
  for (int i = t; i < 2048; i += 256) {
    int r = i >> 5, c4 = (i & 31) * 4;
    float4 v = make_float4(0.f, 0.f, 0.f, 0.f);
    if (row0 + r < N) v = *(const float4*)(x + (size_t)(row0 + r) * 128 + c4);
    uint2 b;                       // packed HW cvt: 2 instrs for 4 values
    b.x = cvt_pk_bf16(v.x, v.y);
    b.y = cvt_pk_bf16(v.z, v.w);
    *(uint2*)&sx[r * 136 + c4] = b;
  }
  __syncthreads();
  const int lane = t & 63, wave = t >> 6;
  const int m = lane & 15, quad = lane >> 4;
  const unsigned short* arow = &sx[(wave * 16 + m) * 136];
  short8 A[4];
#pragma unroll
  for (int ks = 0; ks < 4; ++ks) A[ks] = *(const short8*)&arow[ks * 32 + quad * 8];
  __syncthreads();  // all waves have A in regs; sx region now writable as fp8 tile
  const int lrow = wave * 16 + quad * 4;
#pragma unroll
  for (int nt = 0; nt < 8; ++nt) {
    const unsigned short* brow = &sw[(nt * 16 + m) * 136];
    f32x4 acc = {0.f, 0.f, 0.f, 0.f};
#pragma unroll
    for (int ks = 0; ks < 4; ++ks) {
      short8 B = *(const short8*)&brow[ks * 32 + quad * 8];
      acc = __builtin_amdgcn_mfma_f32_16x16x32_bf16(A[ks], B, acc, 0, 0, 0);
    }
#pragma unroll
    for (int r = 0; r < 4; ++r)
      ftile[(lrow + r) * 128 + nt * 16 + m] = fp8_1(acc[r]);
  }
  __syncthreads();
  // coalesced flush + fused al1 (from the same fp8 values the gather will see)
#pragma unroll
  for (int it = 0; it < 2; ++it) {
    int row = it * 32 + (t >> 3);
    int chunk = t & 7;            // 16-byte chunk = 16 cols; head = chunk>>1
    uint4 v = *(const uint4*)&ftile[row * 128 + chunk * 16];
    int grow = row0 + row;
    if (grow < N) *(uint4*)&h1f[(size_t)grow * 128 + chunk * 16] = v;
    unsigned w[4] = {v.x, v.y, v.z, v.w};
    float ps = 0.f, pd = 0.f;
    int cb = chunk * 16;
#pragma unroll
    for (int q = 0; q < 4; ++q) {
      f32x2 lo = __builtin_amdgcn_cvt_pk_f32_fp8((int)w[q], false);
      f32x2 hi = __builtin_amdgcn_cvt_pk_f32_fp8((int)w[q], true);
      int c = cb + q * 4;
      ps += lo[0] * a1s[c] + lo[1] * a1s[c + 1] + hi[0] * a1s[c + 2] + hi[1] * a1s[c + 3];
      pd += lo[0] * a1d[c] + lo[1] * a1d[c + 1] + hi[0] * a1d[c + 2] + hi[1] * a1d[c + 3];
    }
    ps += __shfl_xor(ps, 1); pd += __shfl_xor(pd, 1);  // pair chunks c, c^1 -> full head
    if ((chunk & 1) == 0 && grow < N) {
      int head = chunk >> 1;
      al1s[(size_t)grow * 4 + head] = ps;
      al1d[(size_t)grow * 4 + head] = pd;
    }
  }
}

__global__ __launch_bounds__(256) void fused_sort_gemm1(
    const void* eidx, int E, int* __restrict__ fillB, unsigned* __restrict__ packed,
    int NB, int NBs,
    const float* __restrict__ x, const unsigned short* __restrict__ w1t,
    const float* __restrict__ a1s, const float* __restrict__ a1d,
    unsigned char* __restrict__ h1f, float* __restrict__ al1s, float* __restrict__ al1d,
    int N) {
  __shared__ __align__(16) char smem[52224];   // max(sortA ~41.9 KB, gemm1 52224 B)
  int bid = blockIdx.x;
  if (bid < NBs) {
    sortA_body(smem, eidx, E, fillB, packed, NB, bid);
  } else {
    gemm1_body(smem, x, w1t, a1s, a1d, h1f, al1s, al1d, N, bid - NBs);
  }
}

__global__ __launch_bounds__(256) void buildCSR_kernel(const unsigned* __restrict__ packed,
                                                       const int* __restrict__ fillB,
                                                       int* __restrict__ rowbeg,
                                                       int* __restrict__ rowend,
                                                       int* __restrict__ csr, int N, int NB) {
  __shared__ int cnt[128], ex[128], fill[128];
  const int b = blockIdx.x;
  const int t = threadIdx.x;
  const int beg = b * BCAP;
  const int end = beg + fillB[b];
  const int node0 = b << 7;
  const int nn = min(128, N - node0);
  if (t < 128) { cnt[t] = 0; fill[t] = 0; }
  __syncthreads();
  for (int i = beg + t; i < end; i += 256) {
    int j = (packed[i] >> 20) & 127;
    atomicAdd(&cnt[j], 1);
  }
  __syncthreads();
  if (t < 128) ex[t] = cnt[t];
  __syncthreads();
  for (int off = 1; off < 128; off <<= 1) {
    int u = (t >= off && t < 128) ? ex[t - off] : 0;
    __syncthreads();
    if (t < 128) ex[t] += u;
    __syncthreads();
  }
  if (t < 128) ex[t] -= cnt[t];  // exclusive
  __syncthreads();
  if (t < nn) {
    rowbeg[node0 + t] = beg + ex[t];
    rowend[node0 + t] = beg + ex[t] + cnt[t];
  }
  for (int i = beg + t; i < end; i += 256) {
    unsigned v = packed[i];
    int j = (v >> 20) & 127;
    int r = atomicAdd(&fill[j], 1);
    csr[beg + ex[j] + r] = (int)(v & 0xFFFFFu);
  }
}

// ---------------- GEMM2 (MFMA bf16): h2f = fp8(houtb @ bf16(W2)), + al2 fused ----------------
__global__ __launch_bounds__(256) void gemm2_mfma(
    const unsigned* __restrict__ houtb, const unsigned short* __restrict__ w2t,
    const float* __restrict__ a2s, const float* __restrict__ a2d,
    unsigned char* __restrict__ h2f, float* __restrict__ al2s, float* __restrict__ al2d, int N) {
  __shared__ unsigned short sw[32 * 136];
  __shared__ unsigned short sx[64 * 136];
  unsigned char* ftile = (unsigned char*)sx;  // 2 KB fp8 tile
  const int t = threadIdx.x;
  const int row0 = blockIdx.x * 64;
  for (int i = t; i < 1024; i += 256) {
    int c = i >> 5, k4 = (i & 31) * 4;
    *(ushort4*)&sw[c * 136 + k4] = *(const ushort4*)&w2t[c * 128 + k4];
  }
  for (int i = t; i < 2048; i += 256) {
    int r = i >> 5, d2 = (i & 31) * 2;
    uint2 v = make_uint2(0u, 0u);
    if (row0 + r < N) v = *(const uint2*)(houtb + (size_t)(row0 + r) * 64 + d2);
    *(uint2*)&sx[r * 136 + d2 * 2] = v;
  }
  __syncthreads();
  const int lane = t & 63, wave = t >> 6;
  const int m = lane & 15, quad = lane >> 4;
  const unsigned short* arow = &sx[(wave * 16 + m) * 136];
  short8 A[4];
#pragma unroll
  for (int ks = 0; ks < 4; ++ks) A[ks] = *(const short8*)&arow[ks * 32 + quad * 8];
  __syncthreads();
  const int lrow = wave * 16 + quad * 4;
#pragma unroll
  for (int nt = 0; nt < 2; ++nt) {
    const unsigned short* brow = &sw[(nt * 16 + m) * 136];
    f32x4 acc = {0.f, 0.f, 0.f, 0.f};
#pragma unroll
    for (int ks = 0; ks < 4; ++ks) {
      short8 B = *(const short8*)&brow[ks * 32 + quad * 8];
      acc = __builtin_amdgcn_mfma_f32_16x16x32_bf16(A[ks], B, acc, 0, 0, 0);
    }
#pragma unroll
    for (int r = 0; r < 4; ++r)
      ftile[(lrow + r) * 32 + nt * 16 + m] = fp8_1(acc[r]);
  }
  __syncthreads();
  if (t < 128) {
    int row = t >> 1, chunk = t & 1;  // 16-byte chunk = 16 of 32 cols
    uint4 v = *(const uint4*)&ftile[row * 32 + chunk * 16];
    int grow = row0 + row;
    if (grow < N) *(uint4*)&h2f[(size_t)grow * 32 + chunk * 16] = v;
    unsigned w[4] = {v.x, v.y, v.z, v.w};
    float ps = 0.f, pd = 0.f;
    int cb = chunk * 16;
#pragma unroll
    for (int q = 0; q < 4; ++q) {
      f32x2 lo = __builtin_amdgcn_cvt_pk_f32_fp8((int)w[q], false);
      f32x2 hi = __builtin_amdgcn_cvt_pk_f32_fp8((int)w[q], true);
      int c = cb + q * 4;
      ps += lo[0] * a2s[c] + lo[1] * a2s[c + 1] + hi[0] * a2s[c + 2] + hi[1] * a2s[c + 3];
      pd += lo[0] * a2d[c] + lo[1] * a2d[c + 1] + hi[0] * a2d[c + 2] + hi[1] * a2d[c + 3];
    }
    ps += __shfl_xor(ps, 1); pd += __shfl_xor(pd, 1);
    if (chunk == 0 && grow < N) { al2s[grow] = ps; al2d[grow] = pd; }
  }
}

// 8-fp8 (uint2) decode + weighted accumulate, PACKED: f32x2 accumulators so LLVM
// selects v_pk_fma_f32 (double-rate packed f32 FMA on gfx950).
#define DEC8P(HV, EX)                                                       \
  {                                                                         \
    f32x2 _e2; _e2[0] = (EX); _e2[1] = (EX);                                \
    acc01 += __builtin_amdgcn_cvt_pk_f32_fp8((int)(HV).x, false) * _e2;     \
    acc23 += __builtin_amdgcn_cvt_pk_f32_fp8((int)(HV).x, true) * _e2;      \
    acc45 += __builtin_amdgcn_cvt_pk_f32_fp8((int)(HV).y, false) * _e2;     \
    acc67 += __builtin_amdgcn_cvt_pk_f32_fp8((int)(HV).y, true) * _e2;      \
    den += (EX);                                                            \
  }

// ---------------- Layer-1 aggregate v5 + GRID-STRIDE ----------------
// R12 PMC: agg1 at Occupancy 68% with VGPR=16 and no LDS — nothing static caps
// it; the deficit is dispatch/drain churn from 25000 short-lived blocks (~4
// nodes each). Per G11: cap grid at 2048 blocks (8/CU), grid-stride over node
// quads so waves stay resident. Per-node body is the converged v5 (bracketed:
// depth v3/v5/v6, VALU trims R2-R4, masking R8, setprio R9).
__global__ __launch_bounds__(256) void agg1_kernel(
    const int* __restrict__ rowbeg, const int* __restrict__ rowend, const int* __restrict__ csr_src,
    const unsigned char* __restrict__ h1f,  // fp8, [N][128]
    const float* __restrict__ al_s, const float* __restrict__ al_d,
    const float* __restrict__ b1, unsigned* __restrict__ houtb, int N) {
  const int t = threadIdx.x;
  const int lane = t & 63;
  const int e_id = lane >> 4;            // which edge of the 4-edge unit
  const unsigned c8 = (unsigned)(lane & 15);  // my 8-col block: cols 8*c8 .. 8*c8+7
  const unsigned head = c8 >> 2;
  const unsigned boff = c8 * 8u;   // byte offset within a payload row
  const int d0 = (int)((blockIdx.x * 256 + t) >> 6);
  const int dstride = (int)(gridDim.x * 4);   // 4 nodes (waves) per block per pass
  for (int d = d0; d < N; d += dstride) {
    const float ald = al_d[(unsigned)d * 4u + head];
    // d is wave-uniform -> bounds in SGPRs, SALU loop
    const int beg = __builtin_amdgcn_readfirstlane(rowbeg[d]);
    const int end = __builtin_amdgcn_readfirstlane(rowend[d]);
    // prefetch iteration 0's csr entries (in flight across the self-loop compute)
    int idx0 = beg + e_id;
    int idx1 = idx0 + 4;
    int sj0 = (idx0 < end) ? csr_src[(unsigned)idx0] : d;
    int sj1 = (idx1 < end) ? csr_src[(unsigned)idx1] : d;
    f32x2 acc01 = {0.f, 0.f}, acc23 = {0.f, 0.f}, acc45 = {0.f, 0.f}, acc67 = {0.f, 0.f};
    float den = 0.f;
    {  // self loop (counted by e_id==0 only; others multiply by 0)
      float e = al_s[(unsigned)d * 4u + head] + ald;
      e = fmaxf(e, 0.2f * e);
      float ex = (e_id == 0) ? __expf(e) : 0.f;
      uint2 hv = *(const uint2*)(h1f + (((unsigned)d << 7) | boff));
      DEC8P(hv, ex);
    }
    for (int i = beg; i < end; i += 8) {
      const int cidx0 = idx0, cidx1 = idx1;
      const int csj0 = sj0, csj1 = sj1;
      // issue current iteration's dependent loads
      float as0 = al_s[(unsigned)csj0 * 4u + head];
      float as1 = al_s[(unsigned)csj1 * 4u + head];
      uint2 hv0 = *(const uint2*)(h1f + (((unsigned)csj0 << 7) | boff));
      uint2 hv1 = *(const uint2*)(h1f + (((unsigned)csj1 << 7) | boff));
      // prefetch next iteration's csr (branchless; masked lanes don't access memory)
      idx0 += 8; idx1 += 8;
      sj0 = (idx0 < end) ? csr_src[(unsigned)idx0] : d;
      sj1 = (idx1 < end) ? csr_src[(unsigned)idx1] : d;
      // compute current
      float e0 = as0 + ald;
      e0 = fmaxf(e0, 0.2f * e0);
      float ex0 = __expf(e0);
      if (cidx0 >= end) ex0 = 0.f;   // mask tail; loop stays branch-free
      float e1 = as1 + ald;
      e1 = fmaxf(e1, 0.2f * e1);
      float ex1 = __expf(e1);
      if (cidx1 >= end) ex1 = 0.f;
      DEC8P(hv0, ex0);
      DEC8P(hv1, ex1);
    }
    // reduce across the 4 e_id groups (lane bits 4,5); disjoint edge sets, same cols
    float a0 = acc01[0], a1 = acc01[1], a2 = acc23[0], a3 = acc23[1];
    float a4 = acc45[0], a5 = acc45[1], a6 = acc67[0], a7 = acc67[1];
    a0 += __shfl_xor(a0, 16); a1 += __shfl_xor(a1, 16);
    a2 += __shfl_xor(a2, 16); a3 += __shfl_xor(a3, 16);
    a4 += __shfl_xor(a4, 16); a5 += __shfl_xor(a5, 16);
    a6 += __shfl_xor(a6, 16); a7 += __shfl_xor(a7, 16);
    den += __shfl_xor(den, 16);
    a0 += __shfl_xor(a0, 32); a1 += __shfl_xor(a1, 32);
    a2 += __shfl_xor(a2, 32); a3 += __shfl_xor(a3, 32);
    a4 += __shfl_xor(a4, 32); a5 += __shfl_xor(a5, 32);
    a6 += __shfl_xor(a6, 32); a7 += __shfl_xor(a7, 32);
    den += __shfl_xor(den, 32);
    // split epilogue: lane (e_id, c8) finishes output pair (2*e_id, 2*e_id+1)
    float inv = __builtin_amdgcn_rcpf(den);
    float p0 = e_id == 0 ? a0 : e_id == 1 ? a2 : e_id == 2 ? a4 : a6;  // static selects
    float p1 = e_id == 0 ? a1 : e_id == 1 ? a3 : e_id == 2 ? a5 : a7;
    float2 bv = *(const float2*)(b1 + 8 * c8 + 2 * e_id);
    float o0 = p0 * inv + bv.x;
    float o1 = p1 * inv + bv.y;
    // ELU; __expf-1 instead of libm expm1f (error << bf16 output rounding)
    o0 = o0 > 0.f ? o0 : __expf(o0) - 1.f;
    o1 = o1 > 0.f ? o1 : __expf(o1) - 1.f;
    houtb[(unsigned)d * 64u + 4u * c8 + (unsigned)e_id] = cvt_pk_bf16(o0, o1);
  }
}

// ---------------- Layer-2 aggregate v6 + GRID-STRIDE + register partials ----------------
// Quarter-wave per node; depth-2 pipeline; split epilogue + rcp. Grid capped at
// 2048 blocks; each thread ACCUMULATES its column-pair across its nodes in
// registers (columns align across iterations) -> single LDS fold per block and
// no per-iteration __syncthreads.
__global__ __launch_bounds__(256) void agg2_kernel(
    const int* __restrict__ rowbeg, const int* __restrict__ rowend, const int* __restrict__ csr_src,
    const unsigned char* __restrict__ h2f,  // fp8, [N][32]
    const float* __restrict__ al_s, const float* __restrict__ al_d,
    float* __restrict__ partial, int N) {
  __shared__ float sp[16 * 32];
  const int t = threadIdx.x;
  const int l16 = t & 15;
  const int slot = t >> 4;       // 16 node-streams per block
  const int e_id = l16 >> 2;     // which edge of the 4-edge unit
  const unsigned c8 = (unsigned)(l16 & 3);  // my 8-col block: cols 8*c8 .. 8*c8+7
  const unsigned boff = c8 * 8u;
  const int n0 = (int)((blockIdx.x * 256 + t) >> 4);
  const int nstride = (int)(gridDim.x * 16);
  float accP0 = 0.f, accP1 = 0.f;   // running sum over my nodes (same columns)
  for (int node = n0; node < N; node += nstride) {
    const float ald = al_d[node];
    const int beg = rowbeg[node], end = rowend[node];
    int idx0 = beg + e_id;
    int idx1 = idx0 + 4;
    int sj0 = (idx0 < end) ? csr_src[(unsigned)idx0] : node;
    int sj1 = (idx1 < end) ? csr_src[(unsigned)idx1] : node;
    float self_as = al_s[node];
    uint2 self_hv = *(const uint2*)(h2f + (((unsigned)node << 5) | boff));
    idx0 += 8; idx1 += 8;
    int nsj0 = (idx0 < end) ? csr_src[(unsigned)idx0] : node;
    int nsj1 = (idx1 < end) ? csr_src[(unsigned)idx1] : node;
    float as0 = al_s[(unsigned)sj0];
    float as1 = al_s[(unsigned)sj1];
    uint2 hv0 = *(const uint2*)(h2f + (((unsigned)sj0 << 5) | boff));
    uint2 hv1 = *(const uint2*)(h2f + (((unsigned)sj1 << 5) | boff));
    f32x2 acc01 = {0.f, 0.f}, acc23 = {0.f, 0.f}, acc45 = {0.f, 0.f}, acc67 = {0.f, 0.f};
    float den = 0.f;
    {  // self loop
      float e = self_as + ald;
      e = fmaxf(e, 0.2f * e);
      float ex = (e_id == 0) ? __expf(e) : 0.f;
      DEC8P(self_hv, ex);
    }
    for (int i = beg; i < end; i += 8) {
      idx0 += 8; idx1 += 8;
      int nnsj0 = (idx0 < end) ? csr_src[(unsigned)idx0] : node;
      int nnsj1 = (idx1 < end) ? csr_src[(unsigned)idx1] : node;
      float nas0 = al_s[(unsigned)nsj0];
      float nas1 = al_s[(unsigned)nsj1];
      uint2 nhv0 = *(const uint2*)(h2f + (((unsigned)nsj0 << 5) | boff));
      uint2 nhv1 = *(const uint2*)(h2f + (((unsigned)nsj1 << 5) | boff));
      int cix0 = i + e_id;
      int cix1 = cix0 + 4;
      float e0 = as0 + ald;
      e0 = fmaxf(e0, 0.2f * e0);
      float ex0 = __expf(e0);
      if (cix0 >= end) ex0 = 0.f;
      float e1 = as1 + ald;
      e1 = fmaxf(e1, 0.2f * e1);
      float ex1 = __expf(e1);
      if (cix1 >= end) ex1 = 0.f;
      DEC8P(hv0, ex0);
      DEC8P(hv1, ex1);
      as0 = nas0; as1 = nas1; hv0 = nhv0; hv1 = nhv1;
      nsj0 = nnsj0; nsj1 = nnsj1;
    }
    // reduce across the 4 e_id groups (l16 bits 2,3)
    float a0 = acc01[0], a1 = acc01[1], a2 = acc23[0], a3 = acc23[1];
    float a4 = acc45[0], a5 = acc45[1], a6 = acc67[0], a7 = acc67[1];
    a0 += __shfl_xor(a0, 4); a1 += __shfl_xor(a1, 4);
    a2 += __shfl_xor(a2, 4); a3 += __shfl_xor(a3, 4);
    a4 += __shfl_xor(a4, 4); a5 += __shfl_xor(a5, 4);
    a6 += __shfl_xor(a6, 4); a7 += __shfl_xor(a7, 4);
    den += __shfl_xor(den, 4);
    a0 += __shfl_xor(a0, 8); a1 += __shfl_xor(a1, 8);
    a2 += __shfl_xor(a2, 8); a3 += __shfl_xor(a3, 8);
    a4 += __shfl_xor(a4, 8); a5 += __shfl_xor(a5, 8);
    a6 += __shfl_xor(a6, 8); a7 += __shfl_xor(a7, 8);
    den += __shfl_xor(den, 8);
    float inv = __builtin_amdgcn_rcpf(den);
    float p0 = e_id == 0 ? a0 : e_id == 1 ? a2 : e_id == 2 ? a4 : a6;
    float p1 = e_id == 0 ? a1 : e_id == 1 ? a3 : e_id == 2 ? a5 : a7;
    accP0 += p0 * inv; accP1 += p1 * inv;
  }
  // one LDS fold per block: lane (slot, e_id, c8) holds column pair (8*c8+2*e_id)
  *(float2*)&sp[slot * 32 + 8 * c8 + 2 * e_id] = make_float2(accP0, accP1);
  __syncthreads();
  if (t < 32) {
    float s = 0.f;
#pragma unroll
    for (int j = 0; j < 16; ++j) s += sp[j * 32 + t];
    partial[(size_t)blockIdx.x * 32 + t] = s;
  }
}

// ---------------- reduce stage: partial[nb][32] -> partial2[128][32] ----------------
// (Parallel fold; the R6 single-block fusion was latency-serial at 57 µs.)
__global__ __launch_bounds__(256) void reduce_kernel(
    const float* __restrict__ partial, int nb, float* __restrict__ partial2) {
  __shared__ float sp[8 * 32];
  int t = threadIdx.x;
  int slot = t >> 5, c = t & 31;
  int row0 = blockIdx.x * 8 + slot;
  float s = 0.f;
  for (int i = row0; i < nb; i += 1024) s += partial[(size_t)i * 32 + c];
  sp[slot * 32 + c] = s;
  __syncthreads();
  if (t < 32) {
    float tot = 0.f;
#pragma unroll
    for (int j = 0; j < 8; ++j) tot += sp[j * 32 + t];
    partial2[(size_t)blockIdx.x * 32 + t] = tot;
  }
}

// ---------------- final: pool mean + linear + softmax ----------------
__global__ void final_kernel(const float* __restrict__ partial2, int nb,
                             const float* __restrict__ b2, const float* __restrict__ linW,
                             const float* __restrict__ linb, float* __restrict__ out, int N) {
  __shared__ float sd[256];
  __shared__ float pooled[32];
  int t = threadIdx.x;
  int c = t & 31, g = t >> 5;
  float s = 0.f;
  for (int i = g; i < nb; i += 8) s += partial2[(size_t)i * 32 + c];
  sd[t] = s; __syncthreads();
  if (t < 32) {
    float tot = 0.f;
#pragma unroll
    for (int j = 0; j < 8; ++j) tot += sd[j * 32 + t];
    pooled[t] = tot / (float)N + b2[t];
  }
  __syncthreads();
  if (t == 0) {
    float lg[3];
    for (int j = 0; j < 3; ++j) lg[j] = linb[j];
    for (int cc = 0; cc < 32; ++cc)
      for (int j = 0; j < 3; ++j) lg[j] += pooled[cc] * linW[cc * 3 + j];
    float m = fmaxf(lg[0], fmaxf(lg[1], lg[2]));
    float e0 = __expf(lg[0] - m), e1 = __expf(lg[1] - m), e2 = __expf(lg[2] - m);
    float inv = 1.f / (e0 + e1 + e2);
    out[0] = e0 * inv; out[1] = e1 * inv; out[2] = e2 * inv;
  }
}

extern "C" void kernel_launch(void* const* d_in, const int* in_sizes, int n_in,
                              void* d_out, int out_size, void* d_ws, size_t ws_size,
                              hipStream_t stream) {
  const float* x    = (const float*)d_in[0];
  const void*  eidx = d_in[1];
  const float* W1   = (const float*)d_in[2];
  const float* a1s  = (const float*)d_in[3];
  const float* a1d  = (const float*)d_in[4];
  const float* b1   = (const float*)d_in[5];
  const float* W2   = (const float*)d_in[6];
  const float* a2s  = (const float*)d_in[7];
  const float* a2d  = (const float*)d_in[8];
  const float* b2   = (const float*)d_in[9];
  const float* linW = (const float*)d_in[10];
  const float* linb = (const float*)d_in[11];
  float* out = (float*)d_out;

  const int N = in_sizes[0] / 128;
  const int E = in_sizes[1] / 2;
  const int NB = (N + 127) >> 7;   // 128-node buckets; must be <= 1024

  char* ws = (char*)d_ws;
  size_t off = 0;
  auto alloc = [&](size_t bytes) -> void* {
    size_t o = off;
    off = align_up(off + bytes, 256);
    return (void*)(ws + o);
  };
  int* fillB  = (int*)alloc((size_t)1024 * sizeof(int));
  int* rowbeg = (int*)alloc((size_t)N * sizeof(int));
  int* rowend = (int*)alloc((size_t)N * sizeof(int));
  unsigned* packed = (unsigned*)alloc((size_t)NB * BCAP * sizeof(unsigned));
  int* csr    = (int*)alloc((size_t)NB * BCAP * sizeof(int));
  float* al1s = (float*)alloc((size_t)N * 4 * sizeof(float));
  float* al1d = (float*)alloc((size_t)N * 4 * sizeof(float));
  float* al2s = (float*)alloc((size_t)N * sizeof(float));
  float* al2d = (float*)alloc((size_t)N * sizeof(float));
  unsigned short* w1t = (unsigned short*)alloc(16384 * sizeof(unsigned short));
  unsigned short* w2t = (unsigned short*)alloc(4096 * sizeof(unsigned short));
  unsigned char* h1f  = (unsigned char*)alloc((size_t)N * 128);  // fp8 [N][128]
  unsigned* houtb = (unsigned*)alloc((size_t)N * 64 * sizeof(unsigned));  // bf16 ELU'd layer-1 out
  unsigned char* h2f  = (unsigned char*)alloc((size_t)N * 32);   // fp8 [N][32]
  const int agg1Blocks = 2048;                         // 8 blocks/CU, grid-stride
  const int agg2Blocks = 2048;
  float* partial  = (float*)alloc((size_t)agg2Blocks * 32 * sizeof(float));
  float* partial2 = (float*)alloc((size_t)128 * 32 * sizeof(float));

  prep_kernel<<<84, 256, 0, stream>>>(W1, W2, w1t, w2t, fillB);

  // sortA and gemm1 are mutually independent (both need only prep outputs):
  // run them concurrently in one grid. sortA batched at 4096 edges/block.
  const int NBs = (E + 4095) / 4096;
  const int gemmBlocks = (N + 63) / 64;
  fused_sort_gemm1<<<NBs + gemmBlocks, 256, 0, stream>>>(
      eidx, E, fillB, packed, NB, NBs, x, w1t, a1s, a1d, h1f, al1s, al1d, N);

  buildCSR_kernel<<<NB, 256, 0, stream>>>(packed, fillB, rowbeg, rowend, csr, N, NB);
  agg1_kernel<<<agg1Blocks, 256, 0, stream>>>(
      rowbeg, rowend, csr, h1f, al1s, al1d, b1, houtb, N);
  gemm2_mfma<<<gemmBlocks, 256, 0, stream>>>(houtb, w2t, a2s, a2d, h2f, al2s, al2d, N);
  agg2_kernel<<<agg2Blocks, 256, 0, stream>>>(
      rowbeg, rowend, csr, h2f, al2s, al2d, partial, N);
  reduce_kernel<<<128, 256, 0, stream>>>(partial, agg2Blocks, partial2);
  final_kernel<<<1, 256, 0, stream>>>(partial2, 128, b2, linW, linb, out, N);
}